// Round 1
// baseline (9348.392 us; speedup 1.0000x reference)
//
#include <hip/hip_runtime.h>
#include <math.h>

#define N_NODES 50000
#define NE      800000
#define NL      8
#define LDH     264    // h row stride: 256 GAT out + 8 labels

__device__ __forceinline__ float elu_f(float x) { return x > 0.f ? x : expf(x) - 1.f; }

// ---------------- time embedding + time MLP (single block) ----------------
__global__ void temb_kernel(const float* __restrict__ t, const int* __restrict__ num_steps,
                            const float* __restrict__ w1, const float* __restrict__ b1,
                            const float* __restrict__ w2, const float* __restrict__ b2,
                            float* __restrict__ temb) {
    __shared__ float emb[128];
    __shared__ float h1[128];
    int tid = threadIdx.x;
    float tv = t[0];
    float ns = (float)num_steps[0];
    float xs = tv / ns * ns * 4.0f;
    if (tid < 64) {
        float fr  = expf((float)tid * (-logf(10000.f) / 63.f));
        float ang = xs * fr;
        emb[tid]      = sinf(ang);
        emb[tid + 64] = cosf(ang);
    }
    __syncthreads();
    if (tid < 128) {
        float a = b1[tid];
        for (int i = 0; i < 128; ++i) a += emb[i] * w1[i * 128 + tid];
        h1[tid] = elu_f(a);
    }
    __syncthreads();
    float a = b2[tid];
    for (int j = 0; j < 128; ++j) a += h1[j] * w2[j * 256 + tid];
    temb[tid] = a;
}

// ---------------- h0 = concat(x, q); also q pinned at cols 256..263 ----------------
__global__ void init_h_kernel(const float* __restrict__ x, const float* __restrict__ q,
                              float* __restrict__ h) {
    int n = blockIdx.x, tid = threadIdx.x;
    if (tid < 128)      h[(size_t)n * LDH + tid] = x[(size_t)n * 128 + tid];
    else if (tid < 136) h[(size_t)n * LDH + tid] = q[(size_t)n * 8 + (tid - 128)];
    else if (tid < 144) h[(size_t)n * LDH + 256 + (tid - 136)] = q[(size_t)n * 8 + (tid - 136)];
}

// ---------------- fp32 tiled GEMM: C[M,NC] = A[M,K](lda) @ B[K,NC](ldb) ----------------
#define BM 128
#define BN 128
#define BK 8
__global__ __launch_bounds__(256) void gemm_kernel(
    const float* __restrict__ A, int lda,
    const float* __restrict__ B, int ldb,
    float* __restrict__ C, int ldc,
    int M, int K, int NC, const float* __restrict__ bias, int act) {
    __shared__ float As[BK][BM];
    __shared__ float Bs[BK][BN];
    int tid  = threadIdx.x;
    int row0 = blockIdx.x * BM;
    int col0 = blockIdx.y * BN;
    int tr = tid >> 4, tc = tid & 15;
    float acc[8][8];
#pragma unroll
    for (int i = 0; i < 8; ++i)
#pragma unroll
        for (int j = 0; j < 8; ++j) acc[i][j] = 0.f;

    int ar = tid >> 1;          // 0..127 row in tile
    int ak = (tid & 1) * 4;     // 0 or 4
    int bk = tid >> 5;          // 0..7
    int bc = (tid & 31) * 4;    // 0..124

    for (int k0 = 0; k0 < K; k0 += BK) {
        float4 av = make_float4(0.f, 0.f, 0.f, 0.f);
        if (row0 + ar < M)
            av = *(const float4*)(A + (size_t)(row0 + ar) * lda + k0 + ak);
        As[ak + 0][ar] = av.x; As[ak + 1][ar] = av.y;
        As[ak + 2][ar] = av.z; As[ak + 3][ar] = av.w;
        float4 bv = make_float4(0.f, 0.f, 0.f, 0.f);
        if (col0 + bc < NC)
            bv = *(const float4*)(B + (size_t)(k0 + bk) * ldb + col0 + bc);
        *(float4*)&Bs[bk][bc] = bv;
        __syncthreads();
#pragma unroll
        for (int kk = 0; kk < BK; ++kk) {
            float4 a0 = *(const float4*)&As[kk][tr * 8];
            float4 a1 = *(const float4*)&As[kk][tr * 8 + 4];
            float4 b0 = *(const float4*)&Bs[kk][tc * 8];
            float4 b1 = *(const float4*)&Bs[kk][tc * 8 + 4];
            float a[8] = {a0.x, a0.y, a0.z, a0.w, a1.x, a1.y, a1.z, a1.w};
            float b[8] = {b0.x, b0.y, b0.z, b0.w, b1.x, b1.y, b1.z, b1.w};
#pragma unroll
            for (int i = 0; i < 8; ++i)
#pragma unroll
                for (int j = 0; j < 8; ++j) acc[i][j] += a[i] * b[j];
        }
        __syncthreads();
    }
#pragma unroll
    for (int i = 0; i < 8; ++i) {
        int r = row0 + tr * 8 + i;
        if (r >= M) break;
#pragma unroll
        for (int j = 0; j < 8; ++j) {
            int c = col0 + tc * 8 + j;
            if (c < NC) {
                float v = acc[i][j];
                if (bias) v += bias[c];
                if (act)  v = elu_f(v);
                C[(size_t)r * ldc + c] = v;
            }
        }
    }
}

// ---------------- attention logits: alpha_s/d[n,h] = <hproj[n,h,:], att[h,:]> ----------------
__global__ void alpha_kernel(const float* __restrict__ hproj,
                             const float* __restrict__ asrc, const float* __restrict__ adst,
                             float* __restrict__ alpha_s, float* __restrict__ alpha_d) {
    int idx = blockIdx.x * blockDim.x + threadIdx.x;
    if (idx >= N_NODES * NL) return;
    int n = idx >> 3, h = idx & 7;
    const float4* hp = (const float4*)(hproj + (size_t)n * 256 + h * 32);
    const float4* a4 = (const float4*)(asrc + h * 32);
    const float4* d4 = (const float4*)(adst + h * 32);
    float s = 0.f, d = 0.f;
#pragma unroll
    for (int i = 0; i < 8; ++i) {
        float4 hv = hp[i], av = a4[i], dv = d4[i];
        s += hv.x * av.x + hv.y * av.y + hv.z * av.z + hv.w * av.w;
        d += hv.x * dv.x + hv.y * dv.y + hv.z * dv.z + hv.w * dv.w;
    }
    alpha_s[idx] = s;
    alpha_d[idx] = d;
}

// ---------------- edge pass: one wave per edge; unnormalized aggregate + denom ----------------
__global__ __launch_bounds__(256) void edge_kernel(
    const int* __restrict__ adj,
    const float* __restrict__ alpha_s, const float* __restrict__ alpha_d,
    const float* __restrict__ hproj,
    float* __restrict__ acc, float* __restrict__ denom) {
    int w    = (blockIdx.x * 256 + threadIdx.x) >> 6;   // edge id
    int lane = threadIdx.x & 63;
    if (w >= NE + N_NODES) return;
    int s, d;
    if (w < NE) { s = adj[w]; d = adj[NE + w]; }
    else        { s = d = w - NE; }                     // self-loop
    int h = lane >> 3;                                  // lane*4 covers c: lane>>3 = head
    float a = alpha_s[s * NL + h] + alpha_d[d * NL + h];
    a = a > 0.f ? a : 0.2f * a;                         // leaky_relu(0.2)
    float ex = expf(a);                                 // softmax shift-invariant: skip segment-max
    float4 hp = ((const float4*)hproj)[(size_t)s * 64 + lane];
    float* ap = acc + (size_t)d * 256 + lane * 4;
    atomicAdd(ap + 0, ex * hp.x);
    atomicAdd(ap + 1, ex * hp.y);
    atomicAdd(ap + 2, ex * hp.z);
    atomicAdd(ap + 3, ex * hp.w);
    if ((lane & 7) == 0) atomicAdd(denom + d * NL + h, ex);
}

// ---------------- node epilogue: h = elu(acc/denom + bias + temb) ----------------
__global__ void node_kernel(const float* __restrict__ acc, const float* __restrict__ denom,
                            const float* __restrict__ bias, const float* __restrict__ temb,
                            float* __restrict__ h) {
    int n = blockIdx.x, c = threadIdx.x;
    float v = acc[(size_t)n * 256 + c] / denom[n * NL + (c >> 5)] + bias[c] + temb[c];
    h[(size_t)n * LDH + c] = elu_f(v);
}

// ---------------- final tiny GEMM: out[N,8] = hmid[N,528] @ w2 + b2 ----------------
__global__ __launch_bounds__(256) void gemm2_kernel(
    const float* __restrict__ hmid, const float* __restrict__ w2,
    const float* __restrict__ b2, float* __restrict__ out) {
    __shared__ float w2s[528 * 8];
    int tid = threadIdx.x;
    for (int i = tid; i < 528 * 8; i += 256) w2s[i] = w2[i];
    __syncthreads();
    int idx = blockIdx.x * 256 + tid;
    if (idx >= N_NODES * NL) return;
    int n = idx >> 3, j = idx & 7;
    float a = b2[j];
    const float4* hp = (const float4*)(hmid + (size_t)n * 528);
    for (int k4 = 0; k4 < 132; ++k4) {
        float4 hv = hp[k4];
        a += hv.x * w2s[(k4 * 4 + 0) * 8 + j] + hv.y * w2s[(k4 * 4 + 1) * 8 + j]
           + hv.z * w2s[(k4 * 4 + 2) * 8 + j] + hv.w * w2s[(k4 * 4 + 3) * 8 + j];
    }
    out[idx] = a;
}

extern "C" void kernel_launch(void* const* d_in, const int* in_sizes, int n_in,
                              void* d_out, int out_size, void* d_ws, size_t ws_size,
                              hipStream_t stream) {
    const float* x   = (const float*)d_in[0];
    const float* q   = (const float*)d_in[1];
    const int*   adj = (const int*)d_in[2];
    const float* t   = (const float*)d_in[3];
    const int*   nst = (const int*)d_in[4];
    const float* W0  = (const float*)d_in[5];
    const float* W1  = (const float*)d_in[6];
    const float* W2  = (const float*)d_in[7];
    const float* att_src = (const float*)d_in[8];
    const float* att_dst = (const float*)d_in[9];
    const float* bias    = (const float*)d_in[10];
    const float* tw1 = (const float*)d_in[11];
    const float* tb1 = (const float*)d_in[12];
    const float* tw2 = (const float*)d_in[13];
    const float* tb2 = (const float*)d_in[14];
    const float* fw1 = (const float*)d_in[15];
    const float* fb1 = (const float*)d_in[16];
    const float* fw2 = (const float*)d_in[17];
    const float* fb2 = (const float*)d_in[18];
    float* out = (float*)d_out;

    char* ws = (char*)d_ws;
    size_t off = 0;
    float* temb    = (float*)(ws + off); off += 1024;
    float* alpha_s = (float*)(ws + off); off += (size_t)N_NODES * NL * 4;
    float* alpha_d = (float*)(ws + off); off += (size_t)N_NODES * NL * 4;
    float* denom   = (float*)(ws + off); off += (size_t)N_NODES * NL * 4;
    float* hbuf    = (float*)(ws + off); off += (size_t)N_NODES * LDH * 4;
    float* big     = (float*)(ws + off);           // 105.6 MB region
    float* hproj   = big;                          // [N,256]
    float* accb    = big + (size_t)N_NODES * 256;  // [N,256]
    float* hmid    = big;                          // [N,528] reuses hproj+accb after layers

    temb_kernel<<<1, 256, 0, stream>>>(t, nst, tw1, tb1, tw2, tb2, temb);
    init_h_kernel<<<N_NODES, 256, 0, stream>>>(x, q, hbuf);

    const float* Ws[3] = {W0, W1, W2};
    for (int l = 0; l < 3; ++l) {
        int K = (l == 0) ? 136 : 264;
        dim3 g((N_NODES + BM - 1) / BM, 2);
        gemm_kernel<<<g, 256, 0, stream>>>(hbuf, LDH, Ws[l], 256, hproj, 256,
                                           N_NODES, K, 256, nullptr, 0);
        alpha_kernel<<<(N_NODES * NL + 255) / 256, 256, 0, stream>>>(
            hproj, att_src + l * 256, att_dst + l * 256, alpha_s, alpha_d);
        hipMemsetAsync(accb, 0, (size_t)N_NODES * 256 * 4, stream);
        hipMemsetAsync(denom, 0, (size_t)N_NODES * NL * 4, stream);
        int nwaves = NE + N_NODES;
        edge_kernel<<<(nwaves * 64 + 255) / 256, 256, 0, stream>>>(
            adj, alpha_s, alpha_d, hproj, accb, denom);
        node_kernel<<<N_NODES, 256, 0, stream>>>(accb, denom, bias + l * 256, temb, hbuf);
    }

    dim3 g1((N_NODES + BM - 1) / BM, (528 + BN - 1) / BN);
    gemm_kernel<<<g1, 256, 0, stream>>>(hbuf, LDH, fw1, 528, hmid, 528,
                                        N_NODES, 264, 528, fb1, 1);
    gemm2_kernel<<<(N_NODES * NL + 255) / 256, 256, 0, stream>>>(hmid, fw2, fb2, out);
}

// Round 2
// 1218.286 us; speedup vs baseline: 7.6734x; 7.6734x over previous
//
#include <hip/hip_runtime.h>
#include <math.h>

#define N_NODES 50000
#define NE      800000
#define NEL     (NE + N_NODES)   // edges incl. self-loops
#define NL      8
#define LDH     264    // h row stride: 256 GAT out + 8 labels

__device__ __forceinline__ float elu_f(float x) { return x > 0.f ? x : __expf(x) - 1.f; }

// ---------------- time embedding + time MLP (single block) ----------------
__global__ void temb_kernel(const float* __restrict__ t, const int* __restrict__ num_steps,
                            const float* __restrict__ w1, const float* __restrict__ b1,
                            const float* __restrict__ w2, const float* __restrict__ b2,
                            float* __restrict__ temb) {
    __shared__ float emb[128];
    __shared__ float h1[128];
    int tid = threadIdx.x;
    float tv = t[0];
    float ns = (float)num_steps[0];
    float xs = tv / ns * ns * 4.0f;
    if (tid < 64) {
        float fr  = expf((float)tid * (-logf(10000.f) / 63.f));
        float ang = xs * fr;
        emb[tid]      = sinf(ang);
        emb[tid + 64] = cosf(ang);
    }
    __syncthreads();
    if (tid < 128) {
        float a = b1[tid];
        for (int i = 0; i < 128; ++i) a += emb[i] * w1[i * 128 + tid];
        h1[tid] = elu_f(a);
    }
    __syncthreads();
    float a = b2[tid];
    for (int j = 0; j < 128; ++j) a += h1[j] * w2[j * 256 + tid];
    temb[tid] = a;
}

// ---------------- h0 = concat(x, q); also q pinned at cols 256..263 ----------------
__global__ void init_h_kernel(const float* __restrict__ x, const float* __restrict__ q,
                              float* __restrict__ h) {
    int n = blockIdx.x, tid = threadIdx.x;
    if (tid < 128)      h[(size_t)n * LDH + tid] = x[(size_t)n * 128 + tid];
    else if (tid < 136) h[(size_t)n * LDH + tid] = q[(size_t)n * 8 + (tid - 128)];
    else if (tid < 144) h[(size_t)n * LDH + 256 + (tid - 136)] = q[(size_t)n * 8 + (tid - 136)];
}

// ================= CSR build (per launch; adj is launch-constant) =================
__global__ void deg_kernel(const int* __restrict__ adj, int* __restrict__ deg) {
    int e = blockIdx.x * 256 + threadIdx.x;
    if (e >= NEL) return;
    int d = (e < NE) ? adj[NE + e] : (e - NE);
    atomicAdd(&deg[d], 1);
}

// single-block exclusive scan over deg[N] -> rowptr[N+1], wptr[N]
__global__ __launch_bounds__(1024) void scan_kernel(const int* __restrict__ deg,
                                                    int* __restrict__ rowptr,
                                                    int* __restrict__ wptr) {
    __shared__ int wsum[16];
    __shared__ int carry;
    int tid = threadIdx.x;
    int lane = tid & 63, wid = tid >> 6;
    if (tid == 0) carry = 0;
    __syncthreads();
    for (int chunk = 0; chunk < N_NODES; chunk += 1024) {
        int idx = chunk + tid;
        int v = (idx < N_NODES) ? deg[idx] : 0;
        int x = v;
#pragma unroll
        for (int off = 1; off < 64; off <<= 1) {
            int tv2 = __shfl_up(x, off);
            if (lane >= off) x += tv2;
        }
        if (lane == 63) wsum[wid] = x;
        __syncthreads();
        if (tid == 0) {
            int run = carry;
#pragma unroll
            for (int w = 0; w < 16; ++w) { int s = wsum[w]; wsum[w] = run; run += s; }
            carry = run;
        }
        __syncthreads();
        int excl = wsum[wid] + x - v;
        if (idx < N_NODES) { rowptr[idx] = excl; wptr[idx] = excl; }
        __syncthreads();   // protect wsum/carry before next chunk
    }
    if (tid == 0) rowptr[N_NODES] = carry;
}

__global__ void scatter_kernel(const int* __restrict__ adj, int* __restrict__ wptr,
                               int* __restrict__ srcs) {
    int e = blockIdx.x * 256 + threadIdx.x;
    if (e >= NEL) return;
    int s, d;
    if (e < NE) { s = adj[e]; d = adj[NE + e]; }
    else        { s = d = e - NE; }
    int pos = atomicAdd(&wptr[d], 1);
    srcs[pos] = s;
}

// ---------------- fp32 tiled GEMM: C[M,NC] = A[M,K](lda) @ B[K,NC](ldb) ----------------
#define BM 128
#define BN 128
#define BK 8
__global__ __launch_bounds__(256) void gemm_kernel(
    const float* __restrict__ A, int lda,
    const float* __restrict__ B, int ldb,
    float* __restrict__ C, int ldc,
    int M, int K, int NC, const float* __restrict__ bias, int act) {
    __shared__ float As[BK][BM];
    __shared__ float Bs[BK][BN];
    int tid  = threadIdx.x;
    int row0 = blockIdx.x * BM;
    int col0 = blockIdx.y * BN;
    int tr = tid >> 4, tc = tid & 15;
    float acc[8][8];
#pragma unroll
    for (int i = 0; i < 8; ++i)
#pragma unroll
        for (int j = 0; j < 8; ++j) acc[i][j] = 0.f;

    int ar = tid >> 1;
    int ak = (tid & 1) * 4;
    int bk = tid >> 5;
    int bc = (tid & 31) * 4;

    for (int k0 = 0; k0 < K; k0 += BK) {
        float4 av = make_float4(0.f, 0.f, 0.f, 0.f);
        if (row0 + ar < M)
            av = *(const float4*)(A + (size_t)(row0 + ar) * lda + k0 + ak);
        As[ak + 0][ar] = av.x; As[ak + 1][ar] = av.y;
        As[ak + 2][ar] = av.z; As[ak + 3][ar] = av.w;
        float4 bv = make_float4(0.f, 0.f, 0.f, 0.f);
        if (col0 + bc < NC)
            bv = *(const float4*)(B + (size_t)(k0 + bk) * ldb + col0 + bc);
        *(float4*)&Bs[bk][bc] = bv;
        __syncthreads();
#pragma unroll
        for (int kk = 0; kk < BK; ++kk) {
            float4 a0 = *(const float4*)&As[kk][tr * 8];
            float4 a1 = *(const float4*)&As[kk][tr * 8 + 4];
            float4 b0 = *(const float4*)&Bs[kk][tc * 8];
            float4 b1 = *(const float4*)&Bs[kk][tc * 8 + 4];
            float a[8] = {a0.x, a0.y, a0.z, a0.w, a1.x, a1.y, a1.z, a1.w};
            float b[8] = {b0.x, b0.y, b0.z, b0.w, b1.x, b1.y, b1.z, b1.w};
#pragma unroll
            for (int i = 0; i < 8; ++i)
#pragma unroll
                for (int j = 0; j < 8; ++j) acc[i][j] += a[i] * b[j];
        }
        __syncthreads();
    }
#pragma unroll
    for (int i = 0; i < 8; ++i) {
        int r = row0 + tr * 8 + i;
        if (r >= M) break;
#pragma unroll
        for (int j = 0; j < 8; ++j) {
            int c = col0 + tc * 8 + j;
            if (c < NC) {
                float v = acc[i][j];
                if (bias) v += bias[c];
                if (act)  v = elu_f(v);
                C[(size_t)r * ldc + c] = v;
            }
        }
    }
}

// ---------------- attention logits: alpha_s/d[n,h] = <hproj[n,h,:], att[h,:]> ----------------
__global__ void alpha_kernel(const float* __restrict__ hproj,
                             const float* __restrict__ asrc, const float* __restrict__ adst,
                             float* __restrict__ alpha_s, float* __restrict__ alpha_d) {
    int idx = blockIdx.x * blockDim.x + threadIdx.x;
    if (idx >= N_NODES * NL) return;
    int n = idx >> 3, h = idx & 7;
    const float4* hp = (const float4*)(hproj + (size_t)n * 256 + h * 32);
    const float4* a4 = (const float4*)(asrc + h * 32);
    const float4* d4 = (const float4*)(adst + h * 32);
    float s = 0.f, d = 0.f;
#pragma unroll
    for (int i = 0; i < 8; ++i) {
        float4 hv = hp[i], av = a4[i], dv = d4[i];
        s += hv.x * av.x + hv.y * av.y + hv.z * av.z + hv.w * av.w;
        d += hv.x * dv.x + hv.y * dv.y + hv.z * dv.z + hv.w * dv.w;
    }
    alpha_s[idx] = s;
    alpha_d[idx] = d;
}

// ======= CSR gather: one wave per dst node; fused normalize+bias+temb+ELU =======
__global__ __launch_bounds__(256) void gather_kernel(
    const int* __restrict__ rowptr, const int* __restrict__ srcs,
    const float* __restrict__ alpha_s, const float* __restrict__ alpha_d,
    const float* __restrict__ hproj, const float* __restrict__ bias,
    const float* __restrict__ temb, float* __restrict__ h) {
    int node = blockIdx.x * 4 + (threadIdx.x >> 6);
    if (node >= N_NODES) return;
    int lane = threadIdx.x & 63;
    int hd = lane >> 3;                    // head for channels 4*lane..4*lane+3
    float ad = alpha_d[node * NL + hd];    // loop-invariant
    int beg = rowptr[node], end = rowptr[node + 1];
    float4 acc = make_float4(0.f, 0.f, 0.f, 0.f);
    float den = 0.f;
    int s_next = (beg < end) ? srcs[beg] : 0;
    for (int i = beg; i < end; ++i) {
        int s = s_next;
        if (i + 1 < end) s_next = srcs[i + 1];
        float a = alpha_s[s * NL + hd] + ad;
        a = a > 0.f ? a : 0.2f * a;        // leaky_relu(0.2)
        float ex = __expf(a);              // softmax shift-invariant: skip segment-max
        float4 hp = ((const float4*)hproj)[(size_t)s * 64 + lane];
        acc.x += ex * hp.x; acc.y += ex * hp.y;
        acc.z += ex * hp.z; acc.w += ex * hp.w;
        den += ex;
    }
    float inv = 1.f / den;                 // den>0: self-loop always present
    int c = lane * 4;
    float4 o;
    o.x = elu_f(acc.x * inv + bias[c + 0] + temb[c + 0]);
    o.y = elu_f(acc.y * inv + bias[c + 1] + temb[c + 1]);
    o.z = elu_f(acc.z * inv + bias[c + 2] + temb[c + 2]);
    o.w = elu_f(acc.w * inv + bias[c + 3] + temb[c + 3]);
    *(float4*)&h[(size_t)node * LDH + c] = o;
}

// ---------------- final tiny GEMM: out[N,8] = hmid[N,528] @ w2 + b2 ----------------
__global__ __launch_bounds__(256) void gemm2_kernel(
    const float* __restrict__ hmid, const float* __restrict__ w2,
    const float* __restrict__ b2, float* __restrict__ out) {
    __shared__ float w2s[528 * 8];
    int tid = threadIdx.x;
    for (int i = tid; i < 528 * 8; i += 256) w2s[i] = w2[i];
    __syncthreads();
    int idx = blockIdx.x * 256 + tid;
    if (idx >= N_NODES * NL) return;
    int n = idx >> 3, j = idx & 7;
    float a = b2[j];
    const float4* hp = (const float4*)(hmid + (size_t)n * 528);
    for (int k4 = 0; k4 < 132; ++k4) {
        float4 hv = hp[k4];
        a += hv.x * w2s[(k4 * 4 + 0) * 8 + j] + hv.y * w2s[(k4 * 4 + 1) * 8 + j]
           + hv.z * w2s[(k4 * 4 + 2) * 8 + j] + hv.w * w2s[(k4 * 4 + 3) * 8 + j];
    }
    out[idx] = a;
}

extern "C" void kernel_launch(void* const* d_in, const int* in_sizes, int n_in,
                              void* d_out, int out_size, void* d_ws, size_t ws_size,
                              hipStream_t stream) {
    const float* x   = (const float*)d_in[0];
    const float* q   = (const float*)d_in[1];
    const int*   adj = (const int*)d_in[2];
    const float* t   = (const float*)d_in[3];
    const int*   nst = (const int*)d_in[4];
    const float* W0  = (const float*)d_in[5];
    const float* W1  = (const float*)d_in[6];
    const float* W2  = (const float*)d_in[7];
    const float* att_src = (const float*)d_in[8];
    const float* att_dst = (const float*)d_in[9];
    const float* bias    = (const float*)d_in[10];
    const float* tw1 = (const float*)d_in[11];
    const float* tb1 = (const float*)d_in[12];
    const float* tw2 = (const float*)d_in[13];
    const float* tb2 = (const float*)d_in[14];
    const float* fw1 = (const float*)d_in[15];
    const float* fb1 = (const float*)d_in[16];
    const float* fw2 = (const float*)d_in[17];
    const float* fb2 = (const float*)d_in[18];
    float* out = (float*)d_out;

    // ---- workspace layout (158.4 MB total) ----
    // [0, 52.8MB): hbuf (persistent)
    // [52.8MB, 158.4MB): layer-phase {hproj 51.2MB, temb, alphas, CSR} ∪ final-phase {hmid 105.6MB}
    char* ws = (char*)d_ws;
    float* hbuf  = (float*)ws;                                  // [N,264]
    char*  reg   = ws + (size_t)N_NODES * LDH * 4;
    float* hproj = (float*)reg;                                 // [N,256]
    float* hmid  = (float*)reg;                                 // [N,528] (final phase)
    char*  sm    = reg + (size_t)N_NODES * 256 * 4;
    float* temb    = (float*)sm;                 sm += 1024;
    float* alpha_s = (float*)sm;                 sm += (size_t)N_NODES * NL * 4;
    float* alpha_d = (float*)sm;                 sm += (size_t)N_NODES * NL * 4;
    int*   deg     = (int*)sm;                   sm += (size_t)N_NODES * 4;       // also wptr
    int*   rowptr  = (int*)sm;                   sm += (size_t)(N_NODES + 1) * 4;
    int*   wptr    = (int*)sm;                   sm += (size_t)N_NODES * 4;
    int*   srcs    = (int*)sm;                   sm += (size_t)NEL * 4;

    temb_kernel<<<1, 256, 0, stream>>>(t, nst, tw1, tb1, tw2, tb2, temb);
    init_h_kernel<<<N_NODES, 256, 0, stream>>>(x, q, hbuf);

    // CSR build (once per launch)
    hipMemsetAsync(deg, 0, (size_t)N_NODES * 4, stream);
    deg_kernel<<<(NEL + 255) / 256, 256, 0, stream>>>(adj, deg);
    scan_kernel<<<1, 1024, 0, stream>>>(deg, rowptr, wptr);
    scatter_kernel<<<(NEL + 255) / 256, 256, 0, stream>>>(adj, wptr, srcs);

    const float* Ws[3] = {W0, W1, W2};
    for (int l = 0; l < 3; ++l) {
        int K = (l == 0) ? 136 : 264;
        dim3 g((N_NODES + BM - 1) / BM, 2);
        gemm_kernel<<<g, 256, 0, stream>>>(hbuf, LDH, Ws[l], 256, hproj, 256,
                                           N_NODES, K, 256, nullptr, 0);
        alpha_kernel<<<(N_NODES * NL + 255) / 256, 256, 0, stream>>>(
            hproj, att_src + l * 256, att_dst + l * 256, alpha_s, alpha_d);
        gather_kernel<<<(N_NODES + 3) / 4, 256, 0, stream>>>(
            rowptr, srcs, alpha_s, alpha_d, hproj, bias + l * 256, temb, hbuf);
    }

    dim3 g1((N_NODES + BM - 1) / BM, (528 + BN - 1) / BN);
    gemm_kernel<<<g1, 256, 0, stream>>>(hbuf, LDH, fw1, 528, hmid, 528,
                                        N_NODES, 264, 528, fb1, 1);
    gemm2_kernel<<<(N_NODES * NL + 255) / 256, 256, 0, stream>>>(hmid, fw2, fb2, out);
}

// Round 4
// 633.841 us; speedup vs baseline: 14.7488x; 1.9221x over previous
//
#include <hip/hip_runtime.h>
#include <math.h>

#define N_NODES 50000
#define NE      800000
#define NEL     (NE + N_NODES)   // edges incl. self-loops
#define NL      8
#define LDHB    288    // hbuf bf16 row stride: 256 GAT out + 8 labels + pad(0)
#define KP0     160    // layer0 Kpad (136 -> 160)
#define KP1     288    // layers1/2 + final Kpad (264 -> 288)

typedef __attribute__((ext_vector_type(8))) short bf16x8;
typedef __attribute__((ext_vector_type(4))) float f32x4;

__device__ __forceinline__ float elu_f(float x) { return x > 0.f ? x : __expf(x) - 1.f; }
__device__ __forceinline__ float bl(unsigned u) { return __uint_as_float(u << 16); }
__device__ __forceinline__ float bh(unsigned u) { return __uint_as_float(u & 0xffff0000u); }
__device__ __forceinline__ unsigned short f2b(float f) {   // RNE f32->bf16
    unsigned u = __float_as_uint(f);
    u += 0x7fff + ((u >> 16) & 1);
    return (unsigned short)(u >> 16);
}

// ---------------- time embedding + time MLP (single block, fp32) ----------------
__global__ void temb_kernel(const float* __restrict__ t, const int* __restrict__ num_steps,
                            const float* __restrict__ w1, const float* __restrict__ b1,
                            const float* __restrict__ w2, const float* __restrict__ b2,
                            float* __restrict__ temb) {
    __shared__ float emb[128];
    __shared__ float h1[128];
    int tid = threadIdx.x;
    float tv = t[0];
    float ns = (float)num_steps[0];
    float xs = tv / ns * ns * 4.0f;
    if (tid < 64) {
        float fr  = expf((float)tid * (-logf(10000.f) / 63.f));
        float ang = xs * fr;
        emb[tid]      = sinf(ang);
        emb[tid + 64] = cosf(ang);
    }
    __syncthreads();
    if (tid < 128) {
        float a = b1[tid];
        for (int i = 0; i < 128; ++i) a += emb[i] * w1[i * 128 + tid];
        h1[tid] = elu_f(a);
    }
    __syncthreads();
    float a = b2[tid];
    for (int j = 0; j < 128; ++j) a += h1[j] * w2[j * 256 + tid];
    temb[tid] = a;
}

// ---------------- hbuf bf16 init: x | q | zeros | q | zeros ----------------
__global__ void init_h_kernel(const float* __restrict__ x, const float* __restrict__ q,
                              unsigned short* __restrict__ h) {
    int n = blockIdx.x, c = threadIdx.x;
    if (c >= LDHB) return;
    float v;
    if (c < 128)      v = x[(size_t)n * 128 + c];
    else if (c < 136) v = q[(size_t)n * 8 + (c - 128)];
    else if (c < 256) v = 0.f;                      // zero so layer0 K-pad (136..159) is clean
    else if (c < 264) v = q[(size_t)n * 8 + (c - 256)];
    else              v = 0.f;                      // K-pad 264..287
    h[(size_t)n * LDHB + c] = f2b(v);
}

// ---------------- weight transpose+pad to bf16: WT[N][Kpad] <- W[K][N] ----------------
__global__ void convw_kernel(const float* __restrict__ W, unsigned short* __restrict__ WT,
                             int K, int N, int Kpad) {
    int idx = blockIdx.x * 256 + threadIdx.x;
    if (idx >= N * Kpad) return;
    int n = idx / Kpad, k = idx - n * Kpad;
    float v = (k < K) ? W[(size_t)k * N + n] : 0.f;
    WT[idx] = f2b(v);
}

// ================= CSR build (per launch) =================
__global__ void deg_kernel(const int* __restrict__ adj, int* __restrict__ deg) {
    int e = blockIdx.x * 256 + threadIdx.x;
    if (e >= NEL) return;
    int d = (e < NE) ? adj[NE + e] : (e - NE);
    atomicAdd(&deg[d], 1);
}

__global__ __launch_bounds__(1024) void scan_kernel(const int* __restrict__ deg,
                                                    int* __restrict__ rowptr,
                                                    int* __restrict__ wptr) {
    __shared__ int wsum[16];
    __shared__ int carry;
    int tid = threadIdx.x;
    int lane = tid & 63, wid = tid >> 6;
    if (tid == 0) carry = 0;
    __syncthreads();
    for (int chunk = 0; chunk < N_NODES; chunk += 1024) {
        int idx = chunk + tid;
        int v = (idx < N_NODES) ? deg[idx] : 0;
        int x = v;
#pragma unroll
        for (int off = 1; off < 64; off <<= 1) {
            int tv2 = __shfl_up(x, off);
            if (lane >= off) x += tv2;
        }
        if (lane == 63) wsum[wid] = x;
        __syncthreads();
        if (tid == 0) {
            int run = carry;
#pragma unroll
            for (int w = 0; w < 16; ++w) { int s = wsum[w]; wsum[w] = run; run += s; }
            carry = run;
        }
        __syncthreads();
        int excl = wsum[wid] + x - v;
        if (idx < N_NODES) { rowptr[idx] = excl; wptr[idx] = excl; }
        __syncthreads();
    }
    if (tid == 0) rowptr[N_NODES] = carry;
}

__global__ void scatter_kernel(const int* __restrict__ adj, int* __restrict__ wptr,
                               int* __restrict__ srcs) {
    int e = blockIdx.x * 256 + threadIdx.x;
    if (e >= NEL) return;
    int s, d;
    if (e < NE) { s = adj[e]; d = adj[NE + e]; }
    else        { s = d = e - NE; }
    int pos = atomicAdd(&wptr[d], 1);
    srcs[pos] = s;
}

// ========== bf16 MFMA GEMM: C[M,NC] = A[M,Kpad](lda) @ Bt[NC,Kpad]^T, bf16 out ==========
// 128x128 tile, 4 waves (2x2), each wave 4x4 frags of 16x16x32. BK=32.
// LDS layout (A and B identical): row r (0..127) stride 64B; k-group kg (0..3, 8 bf16 each)
// stored at slot kgs = kg ^ ((r>>1)&3)  -> 2-way-max bank pattern on ds_read_b128.
__global__ __launch_bounds__(256) void mfma_gemm_kernel(
    const unsigned short* __restrict__ A, int lda,
    const unsigned short* __restrict__ Bt, int ldb,
    unsigned short* __restrict__ C, int ldc,
    int M, int Kpad, int NC, const float* __restrict__ bias, int act) {
    __shared__ char lds[16384];
    char* Asc = lds;
    char* Bsc = lds + 8192;
    int tid  = threadIdx.x;
    int lane = tid & 63, w = tid >> 6;
    int wr = w >> 1, wc = w & 1;
    int row0 = blockIdx.x * 128, col0 = blockIdx.y * 128;

    // staging: 512 slots of 16B per matrix; thread handles slots tid and tid+256
    int s0 = tid, s1 = tid + 256;
    int r0 = s0 >> 2, kg0 = s0 & 3;
    int r1 = s1 >> 2, kg1 = s1 & 3;
    int wa0 = r0 * 64 + ((kg0 ^ ((r0 >> 1) & 3)) << 4);
    int wa1 = r1 * 64 + ((kg1 ^ ((r1 >> 1) & 3)) << 4);
    const unsigned short* Ar0 = A + (size_t)min(row0 + r0, M - 1) * lda + kg0 * 8;
    const unsigned short* Ar1 = A + (size_t)min(row0 + r1, M - 1) * lda + kg1 * 8;
    const unsigned short* Br0 = Bt + (size_t)min(col0 + r0, NC - 1) * ldb + kg0 * 8;
    const unsigned short* Br1 = Bt + (size_t)min(col0 + r1, NC - 1) * ldb + kg1 * 8;

    // fragment read offsets (constant per lane; swizzle matches staging)
    int lr = lane & 15, kgl = lane >> 4;
    int swz = ((kgl ^ ((lr >> 1) & 3)) << 4);
    int abase = (wr * 64 + lr) * 64 + swz;
    int bbase = (wc * 64 + lr) * 64 + swz;

    f32x4 acc[4][4];
#pragma unroll
    for (int m = 0; m < 4; ++m)
#pragma unroll
        for (int n = 0; n < 4; ++n) acc[m][n] = (f32x4){0.f, 0.f, 0.f, 0.f};

    uint4 a0 = *(const uint4*)(Ar0);
    uint4 a1 = *(const uint4*)(Ar1);
    uint4 b0 = *(const uint4*)(Br0);
    uint4 b1 = *(const uint4*)(Br1);

    for (int k0 = 0; k0 < Kpad; k0 += 32) {
        __syncthreads();                       // prev tile's readers done
        *(uint4*)(Asc + wa0) = a0;
        *(uint4*)(Asc + wa1) = a1;
        *(uint4*)(Bsc + wa0) = b0;
        *(uint4*)(Bsc + wa1) = b1;
        if (k0 + 32 < Kpad) {                  // T14: issue next tile early
            a0 = *(const uint4*)(Ar0 + k0 + 32);
            a1 = *(const uint4*)(Ar1 + k0 + 32);
            b0 = *(const uint4*)(Br0 + k0 + 32);
            b1 = *(const uint4*)(Br1 + k0 + 32);
        }
        __syncthreads();                       // staging visible
        bf16x8 af[4], bfr[4];
#pragma unroll
        for (int m = 0; m < 4; ++m) af[m]  = *(const bf16x8*)(Asc + abase + m * 1024);
#pragma unroll
        for (int n = 0; n < 4; ++n) bfr[n] = *(const bf16x8*)(Bsc + bbase + n * 1024);
#pragma unroll
        for (int m = 0; m < 4; ++m)
#pragma unroll
            for (int n = 0; n < 4; ++n)
                acc[m][n] = __builtin_amdgcn_mfma_f32_16x16x32_bf16(af[m], bfr[n], acc[m][n], 0, 0, 0);
    }

#pragma unroll
    for (int m = 0; m < 4; ++m) {
        int rbase = row0 + wr * 64 + m * 16 + (lane >> 4) * 4;
#pragma unroll
        for (int i = 0; i < 4; ++i) {
            int row = rbase + i;
            if (row >= M) continue;
#pragma unroll
            for (int n = 0; n < 4; ++n) {
                int col = col0 + wc * 64 + n * 16 + (lane & 15);
                if (col >= NC) continue;
                float v = acc[m][n][i];
                if (bias) v += bias[col];
                if (act)  v = elu_f(v);
                C[(size_t)row * ldc + col] = f2b(v);
            }
        }
    }
}

// ---------------- attention logits from bf16 hproj ----------------
__global__ void alpha_kernel(const unsigned short* __restrict__ hproj,
                             const float* __restrict__ asrc, const float* __restrict__ adst,
                             float* __restrict__ alpha_s, float* __restrict__ alpha_d) {
    int idx = blockIdx.x * blockDim.x + threadIdx.x;
    if (idx >= N_NODES * NL) return;
    int n = idx >> 3, h = idx & 7;
    const uint4* hp4 = (const uint4*)(hproj + (size_t)n * 256 + h * 32);
    float s = 0.f, d = 0.f;
#pragma unroll
    for (int i = 0; i < 4; ++i) {
        uint4 u = hp4[i];
        float f[8] = {bl(u.x), bh(u.x), bl(u.y), bh(u.y), bl(u.z), bh(u.z), bl(u.w), bh(u.w)};
        int kb = h * 32 + i * 8;
#pragma unroll
        for (int j = 0; j < 8; ++j) {
            s += f[j] * asrc[kb + j];
            d += f[j] * adst[kb + j];
        }
    }
    alpha_s[idx] = s;
    alpha_d[idx] = d;
}

// ======= CSR gather (bf16 hproj): wave per dst node; fused norm+bias+temb+ELU =======
__global__ __launch_bounds__(256) void gather_kernel(
    const int* __restrict__ rowptr, const int* __restrict__ srcs,
    const float* __restrict__ alpha_s, const float* __restrict__ alpha_d,
    const unsigned short* __restrict__ hproj, const float* __restrict__ bias,
    const float* __restrict__ temb, unsigned short* __restrict__ h) {
    int node = blockIdx.x * 4 + (threadIdx.x >> 6);
    if (node >= N_NODES) return;
    int lane = threadIdx.x & 63;
    int hd = lane >> 3;
    float ad = alpha_d[node * NL + hd];
    int beg = rowptr[node], end = rowptr[node + 1];
    float4 acc = make_float4(0.f, 0.f, 0.f, 0.f);
    float den = 0.f;
    const uint2* hp = (const uint2*)hproj;
    int s_next = (beg < end) ? srcs[beg] : 0;
    for (int i = beg; i < end; ++i) {
        int s = s_next;
        if (i + 1 < end) s_next = srcs[i + 1];
        float a = alpha_s[s * NL + hd] + ad;
        a = a > 0.f ? a : 0.2f * a;
        float ex = __expf(a);
        uint2 hv = hp[(size_t)s * 64 + lane];
        acc.x += ex * bl(hv.x); acc.y += ex * bh(hv.x);
        acc.z += ex * bl(hv.y); acc.w += ex * bh(hv.y);
        den += ex;
    }
    float inv = 1.f / den;
    int c = lane * 4;
    ushort4 o;
    o.x = f2b(elu_f(acc.x * inv + bias[c + 0] + temb[c + 0]));
    o.y = f2b(elu_f(acc.y * inv + bias[c + 1] + temb[c + 1]));
    o.z = f2b(elu_f(acc.z * inv + bias[c + 2] + temb[c + 2]));
    o.w = f2b(elu_f(acc.w * inv + bias[c + 3] + temb[c + 3]));
    *(ushort4*)&h[(size_t)node * LDHB + c] = o;
}

// ---------------- final tiny GEMM: out[N,8] = hmid[N,528](bf16) @ w2 + b2 ----------------
__global__ __launch_bounds__(256) void gemm2_kernel(
    const unsigned short* __restrict__ hmid, const float* __restrict__ w2,
    const float* __restrict__ b2, float* __restrict__ out) {
    __shared__ float w2s[528 * 8];
    int tid = threadIdx.x;
    for (int i = tid; i < 528 * 8; i += 256) w2s[i] = w2[i];
    __syncthreads();
    int idx = blockIdx.x * 256 + tid;
    if (idx >= N_NODES * NL) return;
    int n = idx >> 3, j = idx & 7;
    float a = b2[j];
    const uint4* hp = (const uint4*)(hmid + (size_t)n * 528);
    for (int k16 = 0; k16 < 66; ++k16) {
        uint4 u = hp[k16];
        int kb = k16 * 8;
        a += bl(u.x) * w2s[(kb + 0) * 8 + j] + bh(u.x) * w2s[(kb + 1) * 8 + j]
           + bl(u.y) * w2s[(kb + 2) * 8 + j] + bh(u.y) * w2s[(kb + 3) * 8 + j]
           + bl(u.z) * w2s[(kb + 4) * 8 + j] + bh(u.z) * w2s[(kb + 5) * 8 + j]
           + bl(u.w) * w2s[(kb + 6) * 8 + j] + bh(u.w) * w2s[(kb + 7) * 8 + j];
    }
    out[idx] = a;
}

extern "C" void kernel_launch(void* const* d_in, const int* in_sizes, int n_in,
                              void* d_out, int out_size, void* d_ws, size_t ws_size,
                              hipStream_t stream) {
    const float* x   = (const float*)d_in[0];
    const float* q   = (const float*)d_in[1];
    const int*   adj = (const int*)d_in[2];
    const float* t   = (const float*)d_in[3];
    const int*   nst = (const int*)d_in[4];
    const float* W0  = (const float*)d_in[5];
    const float* W1  = (const float*)d_in[6];
    const float* W2  = (const float*)d_in[7];
    const float* att_src = (const float*)d_in[8];
    const float* att_dst = (const float*)d_in[9];
    const float* bias    = (const float*)d_in[10];
    const float* tw1 = (const float*)d_in[11];
    const float* tb1 = (const float*)d_in[12];
    const float* tw2 = (const float*)d_in[13];
    const float* tb2 = (const float*)d_in[14];
    const float* fw1 = (const float*)d_in[15];
    const float* fb1 = (const float*)d_in[16];
    const float* fw2 = (const float*)d_in[17];
    const float* fb2 = (const float*)d_in[18];
    float* out = (float*)d_out;

    // ---- workspace layout (~89 MB) ----
    char* ws = (char*)d_ws;
    unsigned short* hbuf = (unsigned short*)ws;                 // [N,288] bf16, 28.8MB
    char* reg = ws + (size_t)N_NODES * LDHB * 2;
    unsigned short* hproj = (unsigned short*)reg;               // [N,256] bf16 (layer phase)
    unsigned short* hmid  = (unsigned short*)reg;               // [N,528] bf16 (final phase)
    char* sm = reg + (size_t)N_NODES * 528 * 2;
    float* temb    = (float*)sm;              sm += 1024;
    float* alpha_s = (float*)sm;              sm += (size_t)N_NODES * NL * 4;
    float* alpha_d = (float*)sm;              sm += (size_t)N_NODES * NL * 4;
    unsigned short* wt0  = (unsigned short*)sm; sm += (size_t)256 * KP0 * 2;
    unsigned short* wt1  = (unsigned short*)sm; sm += (size_t)256 * KP1 * 2;
    unsigned short* wt2  = (unsigned short*)sm; sm += (size_t)256 * KP1 * 2;
    unsigned short* fw1t = (unsigned short*)sm; sm += (size_t)528 * KP1 * 2;
    int* deg    = (int*)sm;                   sm += (size_t)N_NODES * 4;
    int* rowptr = (int*)sm;                   sm += (size_t)(N_NODES + 4) * 4;
    int* wptr   = (int*)sm;                   sm += (size_t)N_NODES * 4;
    int* srcs   = (int*)sm;                   sm += (size_t)NEL * 4;

    temb_kernel<<<1, 256, 0, stream>>>(t, nst, tw1, tb1, tw2, tb2, temb);
    init_h_kernel<<<N_NODES, 320, 0, stream>>>(x, q, hbuf);

    // weight transpose+pad to bf16
    convw_kernel<<<(256 * KP0 + 255) / 256, 256, 0, stream>>>(W0, wt0, 136, 256, KP0);
    convw_kernel<<<(256 * KP1 + 255) / 256, 256, 0, stream>>>(W1, wt1, 264, 256, KP1);
    convw_kernel<<<(256 * KP1 + 255) / 256, 256, 0, stream>>>(W2, wt2, 264, 256, KP1);
    convw_kernel<<<(528 * KP1 + 255) / 256, 256, 0, stream>>>(fw1, fw1t, 264, 528, KP1);

    // CSR build
    hipMemsetAsync(deg, 0, (size_t)N_NODES * 4, stream);
    deg_kernel<<<(NEL + 255) / 256, 256, 0, stream>>>(adj, deg);
    scan_kernel<<<1, 1024, 0, stream>>>(deg, rowptr, wptr);
    scatter_kernel<<<(NEL + 255) / 256, 256, 0, stream>>>(adj, wptr, srcs);

    const unsigned short* wts[3] = {wt0, wt1, wt2};
    int mblocks = (N_NODES + 127) / 128;
    for (int l = 0; l < 3; ++l) {
        int Kpad = (l == 0) ? KP0 : KP1;
        dim3 g(mblocks, 2);
        mfma_gemm_kernel<<<g, 256, 0, stream>>>(hbuf, LDHB, wts[l], Kpad, hproj, 256,
                                                N_NODES, Kpad, 256, nullptr, 0);
        alpha_kernel<<<(N_NODES * NL + 255) / 256, 256, 0, stream>>>(
            hproj, att_src + l * 256, att_dst + l * 256, alpha_s, alpha_d);
        gather_kernel<<<(N_NODES + 3) / 4, 256, 0, stream>>>(
            rowptr, srcs, alpha_s, alpha_d, hproj, bias + l * 256, temb, hbuf);
    }

    dim3 g1(mblocks, (528 + 127) / 128);
    mfma_gemm_kernel<<<g1, 256, 0, stream>>>(hbuf, LDHB, fw1t, KP1, hmid, 528,
                                             N_NODES, KP1, 528, fb1, 1);
    gemm2_kernel<<<(N_NODES * NL + 255) / 256, 256, 0, stream>>>(hmid, fw2, fb2, out);
}

// Round 5
// 498.057 us; speedup vs baseline: 18.7697x; 1.2726x over previous
//
#include <hip/hip_runtime.h>
#include <math.h>

#define N_NODES 50000
#define NE      800000
#define NEL     (NE + N_NODES)   // edges incl. self-loops
#define NL      8
#define LDHB    288    // hbuf bf16 row stride: 256 GAT out + 8 labels + pad(0)
#define KP0     160    // layer0 Kpad (136 -> 160)
#define KP1     288    // layers1/2 + final Kpad (264 -> 288)
#define NBLK    196    // ceil(N/256) for scan

typedef __attribute__((ext_vector_type(8))) short bf16x8;
typedef __attribute__((ext_vector_type(4))) float f32x4;

__device__ __forceinline__ float elu_f(float x) { return x > 0.f ? x : __expf(x) - 1.f; }
__device__ __forceinline__ float bl(unsigned u) { return __uint_as_float(u << 16); }
__device__ __forceinline__ float bh(unsigned u) { return __uint_as_float(u & 0xffff0000u); }
__device__ __forceinline__ unsigned short f2b(float f) {   // RNE f32->bf16
    unsigned u = __float_as_uint(f);
    u += 0x7fff + ((u >> 16) & 1);
    return (unsigned short)(u >> 16);
}

// ---------------- time embedding + time MLP (single block, fp32) ----------------
__global__ void temb_kernel(const float* __restrict__ t, const int* __restrict__ num_steps,
                            const float* __restrict__ w1, const float* __restrict__ b1,
                            const float* __restrict__ w2, const float* __restrict__ b2,
                            float* __restrict__ temb) {
    __shared__ float emb[128];
    __shared__ float h1[128];
    int tid = threadIdx.x;
    float tv = t[0];
    float ns = (float)num_steps[0];
    float xs = tv / ns * ns * 4.0f;
    if (tid < 64) {
        float fr  = expf((float)tid * (-logf(10000.f) / 63.f));
        float ang = xs * fr;
        emb[tid]      = sinf(ang);
        emb[tid + 64] = cosf(ang);
    }
    __syncthreads();
    if (tid < 128) {
        float a = b1[tid];
        for (int i = 0; i < 128; ++i) a += emb[i] * w1[i * 128 + tid];
        h1[tid] = elu_f(a);
    }
    __syncthreads();
    float a = b2[tid];
    for (int j = 0; j < 128; ++j) a += h1[j] * w2[j * 256 + tid];
    temb[tid] = a;
}

// ---------------- hbuf bf16 init: x | q | zeros | q | zeros ----------------
__global__ void init_h_kernel(const float* __restrict__ x, const float* __restrict__ q,
                              unsigned short* __restrict__ h) {
    int n = blockIdx.x, c = threadIdx.x;
    if (c >= LDHB) return;
    float v;
    if (c < 128)      v = x[(size_t)n * 128 + c];
    else if (c < 136) v = q[(size_t)n * 8 + (c - 128)];
    else if (c < 256) v = 0.f;                      // zero so layer0 K-pad (136..159) is clean
    else if (c < 264) v = q[(size_t)n * 8 + (c - 256)];
    else              v = 0.f;                      // K-pad 264..287
    h[(size_t)n * LDHB + c] = f2b(v);
}

// ---------------- weight transpose+pad to bf16: WT[N][Kpad] <- W[K][N] ----------------
__global__ void convw_kernel(const float* __restrict__ W, unsigned short* __restrict__ WT,
                             int K, int N, int Kpad) {
    int idx = blockIdx.x * 256 + threadIdx.x;
    if (idx >= N * Kpad) return;
    int n = idx / Kpad, k = idx - n * Kpad;
    float v = (k < K) ? W[(size_t)k * N + n] : 0.f;
    WT[idx] = f2b(v);
}

// ================= CSR build (per launch) =================
__global__ void deg_kernel(const int* __restrict__ adj, int* __restrict__ deg) {
    int e = blockIdx.x * 256 + threadIdx.x;
    if (e >= NEL) return;
    int d = (e < NE) ? adj[NE + e] : (e - NE);
    atomicAdd(&deg[d], 1);
}

// 3-kernel multiblock exclusive scan over deg[N]
__global__ void scan1_kernel(const int* __restrict__ deg, int* __restrict__ excl,
                             int* __restrict__ bsum) {
    __shared__ int wsum[4];
    int idx = blockIdx.x * 256 + threadIdx.x;
    int lane = threadIdx.x & 63, wid = threadIdx.x >> 6;
    int v = (idx < N_NODES) ? deg[idx] : 0;
    int x = v;
#pragma unroll
    for (int off = 1; off < 64; off <<= 1) {
        int tv2 = __shfl_up(x, off);
        if (lane >= off) x += tv2;
    }
    if (lane == 63) wsum[wid] = x;
    __syncthreads();
    int woff = 0;
    for (int w = 0; w < wid; ++w) woff += wsum[w];
    if (idx < N_NODES) excl[idx] = woff + x - v;
    if (threadIdx.x == 255) bsum[blockIdx.x] = woff + x;
}

__global__ void scan2_kernel(int* __restrict__ bsum, int* __restrict__ boff) {
    __shared__ int wsum[4];
    int tid = threadIdx.x;
    int lane = tid & 63, wid = tid >> 6;
    int v = (tid < NBLK) ? bsum[tid] : 0;
    int x = v;
#pragma unroll
    for (int off = 1; off < 64; off <<= 1) {
        int tv2 = __shfl_up(x, off);
        if (lane >= off) x += tv2;
    }
    if (lane == 63) wsum[wid] = x;
    __syncthreads();
    int woff = 0;
    for (int w = 0; w < wid; ++w) woff += wsum[w];
    if (tid < NBLK) boff[tid] = woff + x - v;
}

__global__ void scan3_kernel(const int* __restrict__ excl, const int* __restrict__ boff,
                             int* __restrict__ rowptr, int* __restrict__ wptr) {
    int idx = blockIdx.x * 256 + threadIdx.x;
    if (idx < N_NODES) {
        int r = excl[idx] + boff[idx >> 8];
        rowptr[idx] = r;
        wptr[idx] = r;
    }
    if (idx == 0) rowptr[N_NODES] = NEL;
}

__global__ void scatter_kernel(const int* __restrict__ adj, int* __restrict__ wptr,
                               int* __restrict__ srcs) {
    int e = blockIdx.x * 256 + threadIdx.x;
    if (e >= NEL) return;
    int s, d;
    if (e < NE) { s = adj[e]; d = adj[NE + e]; }
    else        { s = d = e - NE; }
    int pos = atomicAdd(&wptr[d], 1);
    srcs[pos] = s;
}

// ========== layer GEMM: hproj[M,256](bf16) = A[M,Kpad] @ Bt[256,Kpad]^T ==========
// Also computes alpha_s/alpha_d[M,8] in the epilogue (shfl_xor reduce over 16 col-lanes).
// 128x128 tile, 4 waves (2x2), each wave 4x4 frags of 16x16x32. BK=32.
// LDS: row r stride 64B; k-group kg stored at slot kg ^ ((r>>1)&3) -> 2-way-max conflicts.
__global__ __launch_bounds__(256) void mfma_gemm_kernel(
    const unsigned short* __restrict__ A, int lda,
    const unsigned short* __restrict__ Bt, int ldb,
    unsigned short* __restrict__ C,
    int M, int Kpad,
    const float* __restrict__ asrc, const float* __restrict__ adst,
    float* __restrict__ alpha_s, float* __restrict__ alpha_d) {
    __shared__ char lds[16384];
    char* Asc = lds;
    char* Bsc = lds + 8192;
    int tid  = threadIdx.x;
    int lane = tid & 63, w = tid >> 6;
    int wr = w >> 1, wc = w & 1;
    int row0 = blockIdx.x * 128, col0 = blockIdx.y * 128;

    int s0i = tid, s1i = tid + 256;
    int r0 = s0i >> 2, kg0 = s0i & 3;
    int r1 = s1i >> 2, kg1 = s1i & 3;
    int wa0 = r0 * 64 + ((kg0 ^ ((r0 >> 1) & 3)) << 4);
    int wa1 = r1 * 64 + ((kg1 ^ ((r1 >> 1) & 3)) << 4);
    const unsigned short* Ar0 = A + (size_t)min(row0 + r0, M - 1) * lda + kg0 * 8;
    const unsigned short* Ar1 = A + (size_t)min(row0 + r1, M - 1) * lda + kg1 * 8;
    const unsigned short* Br0 = Bt + (size_t)(col0 + r0) * ldb + kg0 * 8;
    const unsigned short* Br1 = Bt + (size_t)(col0 + r1) * ldb + kg1 * 8;

    int lr = lane & 15, lq = lane >> 4;
    int swz = ((lq ^ ((lr >> 1) & 3)) << 4);
    int abase = (wr * 64 + lr) * 64 + swz;
    int bbase = (wc * 64 + lr) * 64 + swz;

    f32x4 acc[4][4];
#pragma unroll
    for (int m = 0; m < 4; ++m)
#pragma unroll
        for (int n = 0; n < 4; ++n) acc[m][n] = (f32x4){0.f, 0.f, 0.f, 0.f};

    uint4 a0 = *(const uint4*)(Ar0);
    uint4 a1 = *(const uint4*)(Ar1);
    uint4 b0 = *(const uint4*)(Br0);
    uint4 b1 = *(const uint4*)(Br1);

    for (int k0 = 0; k0 < Kpad; k0 += 32) {
        __syncthreads();
        *(uint4*)(Asc + wa0) = a0;
        *(uint4*)(Asc + wa1) = a1;
        *(uint4*)(Bsc + wa0) = b0;
        *(uint4*)(Bsc + wa1) = b1;
        if (k0 + 32 < Kpad) {
            a0 = *(const uint4*)(Ar0 + k0 + 32);
            a1 = *(const uint4*)(Ar1 + k0 + 32);
            b0 = *(const uint4*)(Br0 + k0 + 32);
            b1 = *(const uint4*)(Br1 + k0 + 32);
        }
        __syncthreads();
        bf16x8 af[4], bfr[4];
#pragma unroll
        for (int m = 0; m < 4; ++m) af[m]  = *(const bf16x8*)(Asc + abase + m * 1024);
#pragma unroll
        for (int n = 0; n < 4; ++n) bfr[n] = *(const bf16x8*)(Bsc + bbase + n * 1024);
#pragma unroll
        for (int m = 0; m < 4; ++m)
#pragma unroll
            for (int n = 0; n < 4; ++n)
                acc[m][n] = __builtin_amdgcn_mfma_f32_16x16x32_bf16(af[m], bfr[n], acc[m][n], 0, 0, 0);
    }

    // per-lane attention weight values for its 4 columns (reused across all rows)
    float asv[4], adv[4];
#pragma unroll
    for (int n = 0; n < 4; ++n) {
        int c = col0 + wc * 64 + n * 16 + lr;   // 0..255
        asv[n] = asrc[c];
        adv[n] = adst[c];
    }
    int h0 = (col0 >> 5) + wc * 2;              // abs head of n=0,1 block

#pragma unroll
    for (int m = 0; m < 4; ++m) {
        int rbase = row0 + wr * 64 + m * 16 + lq * 4;
#pragma unroll
        for (int i = 0; i < 4; ++i) {
            int row = rbase + i;
            // alpha partials over this lane's 4 cols, split per head (n 0,1 | n 2,3)
            float pAs = acc[m][0][i] * asv[0] + acc[m][1][i] * asv[1];
            float pBs = acc[m][2][i] * asv[2] + acc[m][3][i] * asv[3];
            float pAd = acc[m][0][i] * adv[0] + acc[m][1][i] * adv[1];
            float pBd = acc[m][2][i] * adv[2] + acc[m][3][i] * adv[3];
#pragma unroll
            for (int mask = 1; mask < 16; mask <<= 1) {
                pAs += __shfl_xor(pAs, mask);
                pBs += __shfl_xor(pBs, mask);
                pAd += __shfl_xor(pAd, mask);
                pBd += __shfl_xor(pBd, mask);
            }
            if (row < M) {
                if (lr == 0) {
                    alpha_s[row * NL + h0]     = pAs;
                    alpha_s[row * NL + h0 + 1] = pBs;
                    alpha_d[row * NL + h0]     = pAd;
                    alpha_d[row * NL + h0 + 1] = pBd;
                }
#pragma unroll
                for (int n = 0; n < 4; ++n) {
                    int col = col0 + wc * 64 + n * 16 + lr;
                    C[(size_t)row * 256 + col] = f2b(acc[m][n][i]);
                }
            }
        }
    }
}

// ========== final GEMM fused with output projection ==========
// partial[(by*2+wc)][row][8] = sum over this block's col-slice of elu(acc+fb1)*fw2
__global__ __launch_bounds__(256) void fin_gemm_kernel(
    const unsigned short* __restrict__ A, int lda,
    const unsigned short* __restrict__ Bt, int ldb,
    int M, int Kpad,
    const float* __restrict__ fb1, const float* __restrict__ w2,
    float* __restrict__ partial) {
    __shared__ char lds[16384];
    char* Asc = lds;
    char* Bsc = lds + 8192;
    int tid  = threadIdx.x;
    int lane = tid & 63, w = tid >> 6;
    int wr = w >> 1, wc = w & 1;
    int row0 = blockIdx.x * 128, col0 = blockIdx.y * 128;

    int s0i = tid, s1i = tid + 256;
    int r0 = s0i >> 2, kg0 = s0i & 3;
    int r1 = s1i >> 2, kg1 = s1i & 3;
    int wa0 = r0 * 64 + ((kg0 ^ ((r0 >> 1) & 3)) << 4);
    int wa1 = r1 * 64 + ((kg1 ^ ((r1 >> 1) & 3)) << 4);
    const unsigned short* Ar0 = A + (size_t)min(row0 + r0, M - 1) * lda + kg0 * 8;
    const unsigned short* Ar1 = A + (size_t)min(row0 + r1, M - 1) * lda + kg1 * 8;
    const unsigned short* Br0 = Bt + (size_t)min(col0 + r0, 527) * ldb + kg0 * 8;
    const unsigned short* Br1 = Bt + (size_t)min(col0 + r1, 527) * ldb + kg1 * 8;

    int lr = lane & 15, lq = lane >> 4;
    int swz = ((lq ^ ((lr >> 1) & 3)) << 4);
    int abase = (wr * 64 + lr) * 64 + swz;
    int bbase = (wc * 64 + lr) * 64 + swz;

    f32x4 acc[4][4];
#pragma unroll
    for (int m = 0; m < 4; ++m)
#pragma unroll
        for (int n = 0; n < 4; ++n) acc[m][n] = (f32x4){0.f, 0.f, 0.f, 0.f};

    uint4 a0 = *(const uint4*)(Ar0);
    uint4 a1 = *(const uint4*)(Ar1);
    uint4 b0 = *(const uint4*)(Br0);
    uint4 b1 = *(const uint4*)(Br1);

    for (int k0 = 0; k0 < Kpad; k0 += 32) {
        __syncthreads();
        *(uint4*)(Asc + wa0) = a0;
        *(uint4*)(Asc + wa1) = a1;
        *(uint4*)(Bsc + wa0) = b0;
        *(uint4*)(Bsc + wa1) = b1;
        if (k0 + 32 < Kpad) {
            a0 = *(const uint4*)(Ar0 + k0 + 32);
            a1 = *(const uint4*)(Ar1 + k0 + 32);
            b0 = *(const uint4*)(Br0 + k0 + 32);
            b1 = *(const uint4*)(Br1 + k0 + 32);
        }
        __syncthreads();
        bf16x8 af[4], bfr[4];
#pragma unroll
        for (int m = 0; m < 4; ++m) af[m]  = *(const bf16x8*)(Asc + abase + m * 1024);
#pragma unroll
        for (int n = 0; n < 4; ++n) bfr[n] = *(const bf16x8*)(Bsc + bbase + n * 1024);
#pragma unroll
        for (int m = 0; m < 4; ++m)
#pragma unroll
            for (int n = 0; n < 4; ++n)
                acc[m][n] = __builtin_amdgcn_mfma_f32_16x16x32_bf16(af[m], bfr[n], acc[m][n], 0, 0, 0);
    }

    // per-lane: bias + 8 w2 values for each of its 4 cols (col >= 528 -> zeros)
    float fbv[4], w2v[4][8];
#pragma unroll
    for (int n = 0; n < 4; ++n) {
        int c = col0 + wc * 64 + n * 16 + lr;
        if (c < 528) {
            fbv[n] = fb1[c];
            float4 wlo = *(const float4*)(w2 + (size_t)c * 8);
            float4 whi = *(const float4*)(w2 + (size_t)c * 8 + 4);
            w2v[n][0] = wlo.x; w2v[n][1] = wlo.y; w2v[n][2] = wlo.z; w2v[n][3] = wlo.w;
            w2v[n][4] = whi.x; w2v[n][5] = whi.y; w2v[n][6] = whi.z; w2v[n][7] = whi.w;
        } else {
            fbv[n] = 0.f;
#pragma unroll
            for (int j = 0; j < 8; ++j) w2v[n][j] = 0.f;
        }
    }

    float* pbase = partial + (size_t)(blockIdx.y * 2 + wc) * N_NODES * 8;
#pragma unroll
    for (int m = 0; m < 4; ++m) {
        int rbase = row0 + wr * 64 + m * 16 + lq * 4;
#pragma unroll
        for (int i = 0; i < 4; ++i) {
            int row = rbase + i;
            float pj[8];
#pragma unroll
            for (int j = 0; j < 8; ++j) pj[j] = 0.f;
#pragma unroll
            for (int n = 0; n < 4; ++n) {
                float v = elu_f(acc[m][n][i] + fbv[n]);
#pragma unroll
                for (int j = 0; j < 8; ++j) pj[j] += v * w2v[n][j];
            }
#pragma unroll
            for (int mask = 1; mask < 16; mask <<= 1) {
#pragma unroll
                for (int j = 0; j < 8; ++j) pj[j] += __shfl_xor(pj[j], mask);
            }
            if (lr == 0 && row < M) {
                *(float4*)(pbase + (size_t)row * 8)     = make_float4(pj[0], pj[1], pj[2], pj[3]);
                *(float4*)(pbase + (size_t)row * 8 + 4) = make_float4(pj[4], pj[5], pj[6], pj[7]);
            }
        }
    }
}

// ---------------- reduce 10 partials + fb2 -> out ----------------
__global__ void reduce_kernel(const float* __restrict__ partial, const float* __restrict__ fb2,
                              float* __restrict__ out) {
    int idx = blockIdx.x * 256 + threadIdx.x;
    if (idx >= N_NODES * NL) return;
    float a = fb2[idx & 7];
#pragma unroll
    for (int p = 0; p < 10; ++p) a += partial[(size_t)p * N_NODES * 8 + idx];
    out[idx] = a;
}

// ======= CSR gather (bf16 hproj): wave per dst node; 2-edge unroll, scalarized addr =======
__global__ __launch_bounds__(256) void gather_kernel(
    const int* __restrict__ rowptr, const int* __restrict__ srcs,
    const float* __restrict__ alpha_s, const float* __restrict__ alpha_d,
    const unsigned short* __restrict__ hproj, const float* __restrict__ bias,
    const float* __restrict__ temb, unsigned short* __restrict__ h) {
    int node = blockIdx.x * 4 + (threadIdx.x >> 6);
    if (node >= N_NODES) return;
    int lane = threadIdx.x & 63;
    int hd = lane >> 3;
    float ad = alpha_d[node * NL + hd];
    int beg = rowptr[node], end = rowptr[node + 1];
    const uint2* hp = (const uint2*)hproj;
    float4 ac0 = make_float4(0.f, 0.f, 0.f, 0.f);
    float4 ac1 = make_float4(0.f, 0.f, 0.f, 0.f);
    float den0 = 0.f, den1 = 0.f;
    int i = beg;
    int s0 = (i < end) ? srcs[i] : 0;
    int s1 = (i + 1 < end) ? srcs[i + 1] : 0;
    for (; i + 1 < end; i += 2) {
        int u0 = __builtin_amdgcn_readfirstlane(s0);   // edge-uniform -> SGPR addressing
        int u1 = __builtin_amdgcn_readfirstlane(s1);
        s0 = (i + 2 < end) ? srcs[i + 2] : 0;
        s1 = (i + 3 < end) ? srcs[i + 3] : 0;
        float a0 = alpha_s[u0 * NL + hd] + ad;
        float a1 = alpha_s[u1 * NL + hd] + ad;
        a0 = a0 > 0.f ? a0 : 0.2f * a0;
        a1 = a1 > 0.f ? a1 : 0.2f * a1;
        float e0 = __expf(a0);
        float e1 = __expf(a1);
        uint2 h0 = hp[(size_t)u0 * 64 + lane];
        uint2 h1 = hp[(size_t)u1 * 64 + lane];
        ac0.x += e0 * bl(h0.x); ac0.y += e0 * bh(h0.x);
        ac0.z += e0 * bl(h0.y); ac0.w += e0 * bh(h0.y);
        den0 += e0;
        ac1.x += e1 * bl(h1.x); ac1.y += e1 * bh(h1.x);
        ac1.z += e1 * bl(h1.y); ac1.w += e1 * bh(h1.y);
        den1 += e1;
    }
    if (i < end) {                                     // odd tail
        int u0 = __builtin_amdgcn_readfirstlane(s0);
        float a0 = alpha_s[u0 * NL + hd] + ad;
        a0 = a0 > 0.f ? a0 : 0.2f * a0;
        float e0 = __expf(a0);
        uint2 h0 = hp[(size_t)u0 * 64 + lane];
        ac0.x += e0 * bl(h0.x); ac0.y += e0 * bh(h0.x);
        ac0.z += e0 * bl(h0.y); ac0.w += e0 * bh(h0.y);
        den0 += e0;
    }
    float inv = 1.f / (den0 + den1);
    int c = lane * 4;
    ushort4 o;
    o.x = f2b(elu_f((ac0.x + ac1.x) * inv + bias[c + 0] + temb[c + 0]));
    o.y = f2b(elu_f((ac0.y + ac1.y) * inv + bias[c + 1] + temb[c + 1]));
    o.z = f2b(elu_f((ac0.z + ac1.z) * inv + bias[c + 2] + temb[c + 2]));
    o.w = f2b(elu_f((ac0.w + ac1.w) * inv + bias[c + 3] + temb[c + 3]));
    *(ushort4*)&h[(size_t)node * LDHB + c] = o;
}

extern "C" void kernel_launch(void* const* d_in, const int* in_sizes, int n_in,
                              void* d_out, int out_size, void* d_ws, size_t ws_size,
                              hipStream_t stream) {
    const float* x   = (const float*)d_in[0];
    const float* q   = (const float*)d_in[1];
    const int*   adj = (const int*)d_in[2];
    const float* t   = (const float*)d_in[3];
    const int*   nst = (const int*)d_in[4];
    const float* W0  = (const float*)d_in[5];
    const float* W1  = (const float*)d_in[6];
    const float* W2  = (const float*)d_in[7];
    const float* att_src = (const float*)d_in[8];
    const float* att_dst = (const float*)d_in[9];
    const float* bias    = (const float*)d_in[10];
    const float* tw1 = (const float*)d_in[11];
    const float* tb1 = (const float*)d_in[12];
    const float* tw2 = (const float*)d_in[13];
    const float* tb2 = (const float*)d_in[14];
    const float* fw1 = (const float*)d_in[15];
    const float* fb1 = (const float*)d_in[16];
    const float* fw2 = (const float*)d_in[17];
    const float* fb2 = (const float*)d_in[18];
    float* out = (float*)d_out;

    // ---- workspace layout (~80 MB) ----
    char* ws = (char*)d_ws;
    unsigned short* hbuf = (unsigned short*)ws;                   // [N,288] bf16
    char* p = ws + (size_t)N_NODES * LDHB * 2;
    unsigned short* hproj = (unsigned short*)p;  p += (size_t)N_NODES * 256 * 2;
    float* partial = (float*)p;                  p += (size_t)10 * N_NODES * 8 * 4;  // 16MB
    float* temb    = (float*)p;                  p += 1024;
    float* alpha_s = (float*)p;                  p += (size_t)N_NODES * NL * 4;
    float* alpha_d = (float*)p;                  p += (size_t)N_NODES * NL * 4;
    unsigned short* wt0  = (unsigned short*)p;   p += (size_t)256 * KP0 * 2;
    unsigned short* wt1  = (unsigned short*)p;   p += (size_t)256 * KP1 * 2;
    unsigned short* wt2  = (unsigned short*)p;   p += (size_t)256 * KP1 * 2;
    unsigned short* fw1t = (unsigned short*)p;   p += (size_t)528 * KP1 * 2;
    int* deg    = (int*)p;                       p += (size_t)N_NODES * 4;
    int* excl   = (int*)p;                       p += (size_t)N_NODES * 4;
    int* bsum   = (int*)p;                       p += 1024;
    int* boff   = (int*)p;                       p += 1024;
    int* rowptr = (int*)p;                       p += (size_t)(N_NODES + 4) * 4;
    int* wptr   = (int*)p;                       p += (size_t)N_NODES * 4;
    int* srcs   = (int*)p;                       p += (size_t)NEL * 4;

    temb_kernel<<<1, 256, 0, stream>>>(t, nst, tw1, tb1, tw2, tb2, temb);
    init_h_kernel<<<N_NODES, 320, 0, stream>>>(x, q, hbuf);

    convw_kernel<<<(256 * KP0 + 255) / 256, 256, 0, stream>>>(W0, wt0, 136, 256, KP0);
    convw_kernel<<<(256 * KP1 + 255) / 256, 256, 0, stream>>>(W1, wt1, 264, 256, KP1);
    convw_kernel<<<(256 * KP1 + 255) / 256, 256, 0, stream>>>(W2, wt2, 264, 256, KP1);
    convw_kernel<<<(528 * KP1 + 255) / 256, 256, 0, stream>>>(fw1, fw1t, 264, 528, KP1);

    // CSR build
    hipMemsetAsync(deg, 0, (size_t)N_NODES * 4, stream);
    deg_kernel<<<(NEL + 255) / 256, 256, 0, stream>>>(adj, deg);
    scan1_kernel<<<NBLK, 256, 0, stream>>>(deg, excl, bsum);
    scan2_kernel<<<1, 256, 0, stream>>>(bsum, boff);
    scan3_kernel<<<NBLK, 256, 0, stream>>>(excl, boff, rowptr, wptr);
    scatter_kernel<<<(NEL + 255) / 256, 256, 0, stream>>>(adj, wptr, srcs);

    const unsigned short* wts[3] = {wt0, wt1, wt2};
    int mblocks = (N_NODES + 127) / 128;
    for (int l = 0; l < 3; ++l) {
        int Kpad = (l == 0) ? KP0 : KP1;
        dim3 g(mblocks, 2);
        mfma_gemm_kernel<<<g, 256, 0, stream>>>(hbuf, LDHB, wts[l], Kpad, hproj,
                                                N_NODES, Kpad,
                                                att_src + l * 256, att_dst + l * 256,
                                                alpha_s, alpha_d);
        gather_kernel<<<(N_NODES + 3) / 4, 256, 0, stream>>>(
            rowptr, srcs, alpha_s, alpha_d, hproj, bias + l * 256, temb, hbuf);
    }

    dim3 g1(mblocks, 5);
    fin_gemm_kernel<<<g1, 256, 0, stream>>>(hbuf, LDHB, fw1t, KP1, N_NODES, KP1,
                                            fb1, fw2, partial);
    reduce_kernel<<<(N_NODES * NL + 255) / 256, 256, 0, stream>>>(partial, fb2, out);
}

// Round 6
// 481.178 us; speedup vs baseline: 19.4281x; 1.0351x over previous
//
#include <hip/hip_runtime.h>
#include <math.h>

#define N_NODES 50000
#define NE      800000
#define NEL     (NE + N_NODES)   // edges incl. self-loops
#define NL      8
#define LDHB    288    // hbuf bf16 row stride: 256 GAT out + 8 labels + pad(0)
#define KP0     160    // layer0 Kpad (136 -> 160)
#define KP1     288    // layers1/2 + final Kpad (264 -> 288)
#define NBLK    196    // ceil(N/256) for scan

typedef __attribute__((ext_vector_type(8))) short bf16x8;
typedef __attribute__((ext_vector_type(4))) float f32x4;

__device__ __forceinline__ float elu_f(float x) { return x > 0.f ? x : __expf(x) - 1.f; }
__device__ __forceinline__ float bl(unsigned u) { return __uint_as_float(u << 16); }
__device__ __forceinline__ float bh(unsigned u) { return __uint_as_float(u & 0xffff0000u); }
__device__ __forceinline__ unsigned short f2b(float f) {   // RNE f32->bf16
    unsigned u = __float_as_uint(f);
    u += 0x7fff + ((u >> 16) & 1);
    return (unsigned short)(u >> 16);
}
// bijective XCD swizzle (m204): same-row-tile col-blocks land on one XCD
__device__ __forceinline__ int xcd_swizzle(int b, int nwg) {
    int q = nwg >> 3, r = nwg & 7;
    int xcd = b & 7, idx = b >> 3;
    return (xcd < r ? xcd * (q + 1) : r * (q + 1) + (xcd - r) * q) + idx;
}

// ---------------- time embedding + time MLP (single block, fp32) ----------------
__global__ void temb_kernel(const float* __restrict__ t, const int* __restrict__ num_steps,
                            const float* __restrict__ w1, const float* __restrict__ b1,
                            const float* __restrict__ w2, const float* __restrict__ b2,
                            float* __restrict__ temb) {
    __shared__ float emb[128];
    __shared__ float h1[128];
    int tid = threadIdx.x;
    float tv = t[0];
    float ns = (float)num_steps[0];
    float xs = tv / ns * ns * 4.0f;
    if (tid < 64) {
        float fr  = expf((float)tid * (-logf(10000.f) / 63.f));
        float ang = xs * fr;
        emb[tid]      = sinf(ang);
        emb[tid + 64] = cosf(ang);
    }
    __syncthreads();
    if (tid < 128) {
        float a = b1[tid];
        for (int i = 0; i < 128; ++i) a += emb[i] * w1[i * 128 + tid];
        h1[tid] = elu_f(a);
    }
    __syncthreads();
    float a = b2[tid];
    for (int j = 0; j < 128; ++j) a += h1[j] * w2[j * 256 + tid];
    temb[tid] = a;
}

// ---------------- fused prep: hbuf init + 4x weight transpose/pad ----------------
__global__ void prep_kernel(const float* __restrict__ x, const float* __restrict__ q,
                            unsigned short* __restrict__ hbuf,
                            const float* __restrict__ W0, const float* __restrict__ W1,
                            const float* __restrict__ W2, const float* __restrict__ fw1,
                            unsigned short* __restrict__ wt0, unsigned short* __restrict__ wt1,
                            unsigned short* __restrict__ wt2, unsigned short* __restrict__ fw1t) {
    int bid = blockIdx.x, tid = threadIdx.x;
    if (bid < N_NODES) {
        for (int c = tid; c < LDHB; c += 256) {
            float v;
            if (c < 128)      v = x[(size_t)bid * 128 + c];
            else if (c < 136) v = q[(size_t)bid * 8 + (c - 128)];
            else if (c < 256) v = 0.f;                      // layer0 K-pad clean
            else if (c < 264) v = q[(size_t)bid * 8 + (c - 256)];
            else              v = 0.f;                      // K-pad 264..287
            hbuf[(size_t)bid * LDHB + c] = f2b(v);
        }
        return;
    }
    int j = bid - N_NODES;
    const float* W; unsigned short* WT; int K, NN, Kpad, base;
    if (j < 160)      { W = W0;  WT = wt0;  K = 136; NN = 256; Kpad = KP0; base = 0;   }
    else if (j < 448) { W = W1;  WT = wt1;  K = 264; NN = 256; Kpad = KP1; base = 160; }
    else if (j < 736) { W = W2;  WT = wt2;  K = 264; NN = 256; Kpad = KP1; base = 448; }
    else              { W = fw1; WT = fw1t; K = 264; NN = 528; Kpad = KP1; base = 736; }
    int idx = (j - base) * 256 + tid;
    if (idx >= NN * Kpad) return;
    int n = idx / Kpad, k = idx - n * Kpad;
    WT[idx] = f2b(k < K ? W[(size_t)k * NN + n] : 0.f);
}

// ================= CSR build (per launch) =================
__global__ void deg_kernel(const int* __restrict__ adj, int* __restrict__ deg) {
    int e = blockIdx.x * 256 + threadIdx.x;
    if (e >= NEL) return;
    int d = (e < NE) ? adj[NE + e] : (e - NE);
    atomicAdd(&deg[d], 1);
}

__global__ void scan1_kernel(const int* __restrict__ deg, int* __restrict__ excl,
                             int* __restrict__ bsum) {
    __shared__ int wsum[4];
    int idx = blockIdx.x * 256 + threadIdx.x;
    int lane = threadIdx.x & 63, wid = threadIdx.x >> 6;
    int v = (idx < N_NODES) ? deg[idx] : 0;
    int x = v;
#pragma unroll
    for (int off = 1; off < 64; off <<= 1) {
        int tv2 = __shfl_up(x, off);
        if (lane >= off) x += tv2;
    }
    if (lane == 63) wsum[wid] = x;
    __syncthreads();
    int woff = 0;
    for (int w = 0; w < wid; ++w) woff += wsum[w];
    if (idx < N_NODES) excl[idx] = woff + x - v;
    if (threadIdx.x == 255) bsum[blockIdx.x] = woff + x;
}

__global__ void scan2_kernel(int* __restrict__ bsum, int* __restrict__ boff) {
    __shared__ int wsum[4];
    int tid = threadIdx.x;
    int lane = tid & 63, wid = tid >> 6;
    int v = (tid < NBLK) ? bsum[tid] : 0;
    int x = v;
#pragma unroll
    for (int off = 1; off < 64; off <<= 1) {
        int tv2 = __shfl_up(x, off);
        if (lane >= off) x += tv2;
    }
    if (lane == 63) wsum[wid] = x;
    __syncthreads();
    int woff = 0;
    for (int w = 0; w < wid; ++w) woff += wsum[w];
    if (tid < NBLK) boff[tid] = woff + x - v;
}

__global__ void scan3_kernel(const int* __restrict__ excl, const int* __restrict__ boff,
                             int* __restrict__ rowptr, int* __restrict__ wptr) {
    int idx = blockIdx.x * 256 + threadIdx.x;
    if (idx < N_NODES) {
        int r = excl[idx] + boff[idx >> 8];
        rowptr[idx] = r;
        wptr[idx] = r;
    }
    if (idx == 0) rowptr[N_NODES] = NEL;
}

__global__ void scatter_kernel(const int* __restrict__ adj, int* __restrict__ wptr,
                               int* __restrict__ srcs) {
    int e = blockIdx.x * 256 + threadIdx.x;
    if (e >= NEL) return;
    int s, d;
    if (e < NE) { s = adj[e]; d = adj[NE + e]; }
    else        { s = d = e - NE; }
    int pos = atomicAdd(&wptr[d], 1);
    srcs[pos] = s;
}

// ========== layer GEMM: hproj[M,256](bf16) = A[M,Kpad] @ Bt[256,Kpad]^T ==========
// + alpha_s/alpha_d in epilogue. 1D grid, XCD-swizzled, col-fastest (ncb=2).
__global__ __launch_bounds__(256) void mfma_gemm_kernel(
    const unsigned short* __restrict__ A, int lda,
    const unsigned short* __restrict__ Bt, int ldb,
    unsigned short* __restrict__ C,
    int M, int Kpad,
    const float* __restrict__ asrc, const float* __restrict__ adst,
    float* __restrict__ alpha_s, float* __restrict__ alpha_d) {
    __shared__ char lds[16384];
    char* Asc = lds;
    char* Bsc = lds + 8192;
    int wg = xcd_swizzle(blockIdx.x, gridDim.x);
    int row0 = (wg >> 1) * 128, col0 = (wg & 1) * 128;
    int tid  = threadIdx.x;
    int lane = tid & 63, w = tid >> 6;
    int wr = w >> 1, wc = w & 1;

    int s0i = tid, s1i = tid + 256;
    int r0 = s0i >> 2, kg0 = s0i & 3;
    int r1 = s1i >> 2, kg1 = s1i & 3;
    int wa0 = r0 * 64 + ((kg0 ^ ((r0 >> 1) & 3)) << 4);
    int wa1 = r1 * 64 + ((kg1 ^ ((r1 >> 1) & 3)) << 4);
    const unsigned short* Ar0 = A + (size_t)min(row0 + r0, M - 1) * lda + kg0 * 8;
    const unsigned short* Ar1 = A + (size_t)min(row0 + r1, M - 1) * lda + kg1 * 8;
    const unsigned short* Br0 = Bt + (size_t)(col0 + r0) * ldb + kg0 * 8;
    const unsigned short* Br1 = Bt + (size_t)(col0 + r1) * ldb + kg1 * 8;

    int lr = lane & 15, lq = lane >> 4;
    int swz = ((lq ^ ((lr >> 1) & 3)) << 4);
    int abase = (wr * 64 + lr) * 64 + swz;
    int bbase = (wc * 64 + lr) * 64 + swz;

    f32x4 acc[4][4];
#pragma unroll
    for (int m = 0; m < 4; ++m)
#pragma unroll
        for (int n = 0; n < 4; ++n) acc[m][n] = (f32x4){0.f, 0.f, 0.f, 0.f};

    uint4 a0 = *(const uint4*)(Ar0);
    uint4 a1 = *(const uint4*)(Ar1);
    uint4 b0 = *(const uint4*)(Br0);
    uint4 b1 = *(const uint4*)(Br1);

    for (int k0 = 0; k0 < Kpad; k0 += 32) {
        __syncthreads();
        *(uint4*)(Asc + wa0) = a0;
        *(uint4*)(Asc + wa1) = a1;
        *(uint4*)(Bsc + wa0) = b0;
        *(uint4*)(Bsc + wa1) = b1;
        if (k0 + 32 < Kpad) {
            a0 = *(const uint4*)(Ar0 + k0 + 32);
            a1 = *(const uint4*)(Ar1 + k0 + 32);
            b0 = *(const uint4*)(Br0 + k0 + 32);
            b1 = *(const uint4*)(Br1 + k0 + 32);
        }
        __syncthreads();
        bf16x8 af[4], bfr[4];
#pragma unroll
        for (int m = 0; m < 4; ++m) af[m]  = *(const bf16x8*)(Asc + abase + m * 1024);
#pragma unroll
        for (int n = 0; n < 4; ++n) bfr[n] = *(const bf16x8*)(Bsc + bbase + n * 1024);
#pragma unroll
        for (int m = 0; m < 4; ++m)
#pragma unroll
            for (int n = 0; n < 4; ++n)
                acc[m][n] = __builtin_amdgcn_mfma_f32_16x16x32_bf16(af[m], bfr[n], acc[m][n], 0, 0, 0);
    }

    float asv[4], adv[4];
#pragma unroll
    for (int n = 0; n < 4; ++n) {
        int c = col0 + wc * 64 + n * 16 + lr;
        asv[n] = asrc[c];
        adv[n] = adst[c];
    }
    int h0 = (col0 >> 5) + wc * 2;

#pragma unroll
    for (int m = 0; m < 4; ++m) {
        int rbase = row0 + wr * 64 + m * 16 + lq * 4;
#pragma unroll
        for (int i = 0; i < 4; ++i) {
            int row = rbase + i;
            float pAs = acc[m][0][i] * asv[0] + acc[m][1][i] * asv[1];
            float pBs = acc[m][2][i] * asv[2] + acc[m][3][i] * asv[3];
            float pAd = acc[m][0][i] * adv[0] + acc[m][1][i] * adv[1];
            float pBd = acc[m][2][i] * adv[2] + acc[m][3][i] * adv[3];
#pragma unroll
            for (int mask = 1; mask < 16; mask <<= 1) {
                pAs += __shfl_xor(pAs, mask);
                pBs += __shfl_xor(pBs, mask);
                pAd += __shfl_xor(pAd, mask);
                pBd += __shfl_xor(pBd, mask);
            }
            if (row < M) {
                if (lr == 0) {
                    alpha_s[row * NL + h0]     = pAs;
                    alpha_s[row * NL + h0 + 1] = pBs;
                    alpha_d[row * NL + h0]     = pAd;
                    alpha_d[row * NL + h0 + 1] = pBd;
                }
#pragma unroll
                for (int n = 0; n < 4; ++n) {
                    int col = col0 + wc * 64 + n * 16 + lr;
                    C[(size_t)row * 256 + col] = f2b(acc[m][n][i]);
                }
            }
        }
    }
}

// ========== final GEMM fused with output projection (ncb=5, XCD-swizzled) ==========
__global__ __launch_bounds__(256) void fin_gemm_kernel(
    const unsigned short* __restrict__ A, int lda,
    const unsigned short* __restrict__ Bt, int ldb,
    int M, int Kpad,
    const float* __restrict__ fb1, const float* __restrict__ w2,
    float* __restrict__ partial) {
    __shared__ char lds[16384];
    char* Asc = lds;
    char* Bsc = lds + 8192;
    int wg = xcd_swizzle(blockIdx.x, gridDim.x);
    int by = wg % 5, bx = wg / 5;
    int row0 = bx * 128, col0 = by * 128;
    int tid  = threadIdx.x;
    int lane = tid & 63, w = tid >> 6;
    int wr = w >> 1, wc = w & 1;

    int s0i = tid, s1i = tid + 256;
    int r0 = s0i >> 2, kg0 = s0i & 3;
    int r1 = s1i >> 2, kg1 = s1i & 3;
    int wa0 = r0 * 64 + ((kg0 ^ ((r0 >> 1) & 3)) << 4);
    int wa1 = r1 * 64 + ((kg1 ^ ((r1 >> 1) & 3)) << 4);
    const unsigned short* Ar0 = A + (size_t)min(row0 + r0, M - 1) * lda + kg0 * 8;
    const unsigned short* Ar1 = A + (size_t)min(row0 + r1, M - 1) * lda + kg1 * 8;
    const unsigned short* Br0 = Bt + (size_t)min(col0 + r0, 527) * ldb + kg0 * 8;
    const unsigned short* Br1 = Bt + (size_t)min(col0 + r1, 527) * ldb + kg1 * 8;

    int lr = lane & 15, lq = lane >> 4;
    int swz = ((lq ^ ((lr >> 1) & 3)) << 4);
    int abase = (wr * 64 + lr) * 64 + swz;
    int bbase = (wc * 64 + lr) * 64 + swz;

    f32x4 acc[4][4];
#pragma unroll
    for (int m = 0; m < 4; ++m)
#pragma unroll
        for (int n = 0; n < 4; ++n) acc[m][n] = (f32x4){0.f, 0.f, 0.f, 0.f};

    uint4 a0 = *(const uint4*)(Ar0);
    uint4 a1 = *(const uint4*)(Ar1);
    uint4 b0 = *(const uint4*)(Br0);
    uint4 b1 = *(const uint4*)(Br1);

    for (int k0 = 0; k0 < Kpad; k0 += 32) {
        __syncthreads();
        *(uint4*)(Asc + wa0) = a0;
        *(uint4*)(Asc + wa1) = a1;
        *(uint4*)(Bsc + wa0) = b0;
        *(uint4*)(Bsc + wa1) = b1;
        if (k0 + 32 < Kpad) {
            a0 = *(const uint4*)(Ar0 + k0 + 32);
            a1 = *(const uint4*)(Ar1 + k0 + 32);
            b0 = *(const uint4*)(Br0 + k0 + 32);
            b1 = *(const uint4*)(Br1 + k0 + 32);
        }
        __syncthreads();
        bf16x8 af[4], bfr[4];
#pragma unroll
        for (int m = 0; m < 4; ++m) af[m]  = *(const bf16x8*)(Asc + abase + m * 1024);
#pragma unroll
        for (int n = 0; n < 4; ++n) bfr[n] = *(const bf16x8*)(Bsc + bbase + n * 1024);
#pragma unroll
        for (int m = 0; m < 4; ++m)
#pragma unroll
            for (int n = 0; n < 4; ++n)
                acc[m][n] = __builtin_amdgcn_mfma_f32_16x16x32_bf16(af[m], bfr[n], acc[m][n], 0, 0, 0);
    }

    float fbv[4], w2v[4][8];
#pragma unroll
    for (int n = 0; n < 4; ++n) {
        int c = col0 + wc * 64 + n * 16 + lr;
        if (c < 528) {
            fbv[n] = fb1[c];
            float4 wlo = *(const float4*)(w2 + (size_t)c * 8);
            float4 whi = *(const float4*)(w2 + (size_t)c * 8 + 4);
            w2v[n][0] = wlo.x; w2v[n][1] = wlo.y; w2v[n][2] = wlo.z; w2v[n][3] = wlo.w;
            w2v[n][4] = whi.x; w2v[n][5] = whi.y; w2v[n][6] = whi.z; w2v[n][7] = whi.w;
        } else {
            fbv[n] = 0.f;
#pragma unroll
            for (int j = 0; j < 8; ++j) w2v[n][j] = 0.f;
        }
    }

    float* pbase = partial + (size_t)(by * 2 + wc) * N_NODES * 8;
#pragma unroll
    for (int m = 0; m < 4; ++m) {
        int rbase = row0 + wr * 64 + m * 16 + lq * 4;
#pragma unroll
        for (int i = 0; i < 4; ++i) {
            int row = rbase + i;
            float pj[8];
#pragma unroll
            for (int j = 0; j < 8; ++j) pj[j] = 0.f;
#pragma unroll
            for (int n = 0; n < 4; ++n) {
                float v = elu_f(acc[m][n][i] + fbv[n]);
#pragma unroll
                for (int j = 0; j < 8; ++j) pj[j] += v * w2v[n][j];
            }
#pragma unroll
            for (int mask = 1; mask < 16; mask <<= 1) {
#pragma unroll
                for (int j = 0; j < 8; ++j) pj[j] += __shfl_xor(pj[j], mask);
            }
            if (lr == 0 && row < M) {
                *(float4*)(pbase + (size_t)row * 8)     = make_float4(pj[0], pj[1], pj[2], pj[3]);
                *(float4*)(pbase + (size_t)row * 8 + 4) = make_float4(pj[4], pj[5], pj[6], pj[7]);
            }
        }
    }
}

// ---------------- reduce 10 partials + fb2 -> out ----------------
__global__ void reduce_kernel(const float* __restrict__ partial, const float* __restrict__ fb2,
                              float* __restrict__ out) {
    int idx = blockIdx.x * 256 + threadIdx.x;
    if (idx >= N_NODES * NL) return;
    float a = fb2[idx & 7];
#pragma unroll
    for (int p = 0; p < 10; ++p) a += partial[(size_t)p * N_NODES * 8 + idx];
    out[idx] = a;
}

// ======= CSR gather: wave per node; half-wave edge pairing (32 lanes x 8ch each) =======
__global__ __launch_bounds__(256) void gather_kernel(
    const int* __restrict__ rowptr, const int* __restrict__ srcs,
    const float* __restrict__ alpha_s, const float* __restrict__ alpha_d,
    const unsigned short* __restrict__ hproj, const float* __restrict__ bias,
    const float* __restrict__ temb, unsigned short* __restrict__ h) {
    int node = blockIdx.x * 4 + (threadIdx.x >> 6);
    int lane = threadIdx.x & 63;
    int half = lane >> 5;          // edge parity handled by this half-wave
    int l32  = lane & 31;          // channel block: ch = l32*8 .. +7
    int hd   = l32 >> 2;           // head of these 8 channels
    float ad = alpha_d[node * NL + hd];
    int beg = rowptr[node], end = rowptr[node + 1];
    const uint4* hp4 = (const uint4*)hproj;   // 32 uint4 per 256-ch row
    float ac0[8], ac1[8];
#pragma unroll
    for (int j = 0; j < 8; ++j) { ac0[j] = 0.f; ac1[j] = 0.f; }
    float den0 = 0.f, den1 = 0.f;
    int i = beg + half;
    for (; i + 2 < end; i += 4) {              // dual chain: edges i and i+2
        int sA = srcs[i], sB = srcs[i + 2];
        float aA = alpha_s[sA * NL + hd] + ad;
        float aB = alpha_s[sB * NL + hd] + ad;
        aA = aA > 0.f ? aA : 0.2f * aA;
        aB = aB > 0.f ? aB : 0.2f * aB;
        float eA = __expf(aA);
        float eB = __expf(aB);
        uint4 hA = hp4[(size_t)sA * 32 + l32];
        uint4 hB = hp4[(size_t)sB * 32 + l32];
        ac0[0] += eA * bl(hA.x); ac0[1] += eA * bh(hA.x);
        ac0[2] += eA * bl(hA.y); ac0[3] += eA * bh(hA.y);
        ac0[4] += eA * bl(hA.z); ac0[5] += eA * bh(hA.z);
        ac0[6] += eA * bl(hA.w); ac0[7] += eA * bh(hA.w);
        den0 += eA;
        ac1[0] += eB * bl(hB.x); ac1[1] += eB * bh(hB.x);
        ac1[2] += eB * bl(hB.y); ac1[3] += eB * bh(hB.y);
        ac1[4] += eB * bl(hB.z); ac1[5] += eB * bh(hB.z);
        ac1[6] += eB * bl(hB.w); ac1[7] += eB * bh(hB.w);
        den1 += eB;
    }
    for (; i < end; i += 2) {                  // at most 1 iteration
        int sA = srcs[i];
        float aA = alpha_s[sA * NL + hd] + ad;
        aA = aA > 0.f ? aA : 0.2f * aA;
        float eA = __expf(aA);
        uint4 hA = hp4[(size_t)sA * 32 + l32];
        ac0[0] += eA * bl(hA.x); ac0[1] += eA * bh(hA.x);
        ac0[2] += eA * bl(hA.y); ac0[3] += eA * bh(hA.y);
        ac0[4] += eA * bl(hA.z); ac0[5] += eA * bh(hA.z);
        ac0[6] += eA * bl(hA.w); ac0[7] += eA * bh(hA.w);
        den0 += eA;
    }
    float den = den0 + den1;
    den += __shfl_xor(den, 32);                // merge half-waves
    float av[8];
#pragma unroll
    for (int j = 0; j < 8; ++j) {
        av[j] = ac0[j] + ac1[j];
        av[j] += __shfl_xor(av[j], 32);
    }
    if (half == 0) {
        float inv = 1.f / den;                 // den>0: self-loop always present
        int c = l32 * 8;
        float4 b0 = *(const float4*)(bias + c);
        float4 b1 = *(const float4*)(bias + c + 4);
        float4 t0 = *(const float4*)(temb + c);
        float4 t1 = *(const float4*)(temb + c + 4);
        unsigned o[4];
        o[0] = (unsigned)f2b(elu_f(av[0] * inv + b0.x + t0.x))
             | ((unsigned)f2b(elu_f(av[1] * inv + b0.y + t0.y)) << 16);
        o[1] = (unsigned)f2b(elu_f(av[2] * inv + b0.z + t0.z))
             | ((unsigned)f2b(elu_f(av[3] * inv + b0.w + t0.w)) << 16);
        o[2] = (unsigned)f2b(elu_f(av[4] * inv + b1.x + t1.x))
             | ((unsigned)f2b(elu_f(av[5] * inv + b1.y + t1.y)) << 16);
        o[3] = (unsigned)f2b(elu_f(av[6] * inv + b1.z + t1.z))
             | ((unsigned)f2b(elu_f(av[7] * inv + b1.w + t1.w)) << 16);
        *(uint4*)&h[(size_t)node * LDHB + c] = make_uint4(o[0], o[1], o[2], o[3]);
    }
}

extern "C" void kernel_launch(void* const* d_in, const int* in_sizes, int n_in,
                              void* d_out, int out_size, void* d_ws, size_t ws_size,
                              hipStream_t stream) {
    const float* x   = (const float*)d_in[0];
    const float* q   = (const float*)d_in[1];
    const int*   adj = (const int*)d_in[2];
    const float* t   = (const float*)d_in[3];
    const int*   nst = (const int*)d_in[4];
    const float* W0  = (const float*)d_in[5];
    const float* W1  = (const float*)d_in[6];
    const float* W2  = (const float*)d_in[7];
    const float* att_src = (const float*)d_in[8];
    const float* att_dst = (const float*)d_in[9];
    const float* bias    = (const float*)d_in[10];
    const float* tw1 = (const float*)d_in[11];
    const float* tb1 = (const float*)d_in[12];
    const float* tw2 = (const float*)d_in[13];
    const float* tb2 = (const float*)d_in[14];
    const float* fw1 = (const float*)d_in[15];
    const float* fb1 = (const float*)d_in[16];
    const float* fw2 = (const float*)d_in[17];
    const float* fb2 = (const float*)d_in[18];
    float* out = (float*)d_out;

    // ---- workspace layout (~80 MB) ----
    char* ws = (char*)d_ws;
    unsigned short* hbuf = (unsigned short*)ws;                   // [N,288] bf16
    char* p = ws + (size_t)N_NODES * LDHB * 2;
    unsigned short* hproj = (unsigned short*)p;  p += (size_t)N_NODES * 256 * 2;
    float* partial = (float*)p;                  p += (size_t)10 * N_NODES * 8 * 4;  // 16MB
    float* temb    = (float*)p;                  p += 1024;
    float* alpha_s = (float*)p;                  p += (size_t)N_NODES * NL * 4;
    float* alpha_d = (float*)p;                  p += (size_t)N_NODES * NL * 4;
    unsigned short* wt0  = (unsigned short*)p;   p += (size_t)256 * KP0 * 2;
    unsigned short* wt1  = (unsigned short*)p;   p += (size_t)256 * KP1 * 2;
    unsigned short* wt2  = (unsigned short*)p;   p += (size_t)256 * KP1 * 2;
    unsigned short* fw1t = (unsigned short*)p;   p += (size_t)528 * KP1 * 2;
    int* deg    = (int*)p;                       p += (size_t)N_NODES * 4;
    int* excl   = (int*)p;                       p += (size_t)N_NODES * 4;
    int* bsum   = (int*)p;                       p += 1024;
    int* boff   = (int*)p;                       p += 1024;
    int* rowptr = (int*)p;                       p += (size_t)(N_NODES + 4) * 4;
    int* wptr   = (int*)p;                       p += (size_t)N_NODES * 4;
    int* srcs   = (int*)p;                       p += (size_t)NEL * 4;

    temb_kernel<<<1, 256, 0, stream>>>(t, nst, tw1, tb1, tw2, tb2, temb);
    prep_kernel<<<N_NODES + 1330, 256, 0, stream>>>(x, q, hbuf, W0, W1, W2, fw1,
                                                    wt0, wt1, wt2, fw1t);

    // CSR build
    hipMemsetAsync(deg, 0, (size_t)N_NODES * 4, stream);
    deg_kernel<<<(NEL + 255) / 256, 256, 0, stream>>>(adj, deg);
    scan1_kernel<<<NBLK, 256, 0, stream>>>(deg, excl, bsum);
    scan2_kernel<<<1, 256, 0, stream>>>(bsum, boff);
    scan3_kernel<<<NBLK, 256, 0, stream>>>(excl, boff, rowptr, wptr);
    scatter_kernel<<<(NEL + 255) / 256, 256, 0, stream>>>(adj, wptr, srcs);

    const unsigned short* wts[3] = {wt0, wt1, wt2};
    int mblocks = (N_NODES + 127) / 128;       // 391
    for (int l = 0; l < 3; ++l) {
        int Kpad = (l == 0) ? KP0 : KP1;
        mfma_gemm_kernel<<<mblocks * 2, 256, 0, stream>>>(hbuf, LDHB, wts[l], Kpad, hproj,
                                                          N_NODES, Kpad,
                                                          att_src + l * 256, att_dst + l * 256,
                                                          alpha_s, alpha_d);
        gather_kernel<<<(N_NODES + 3) / 4, 256, 0, stream>>>(
            rowptr, srcs, alpha_s, alpha_d, hproj, bias + l * 256, temb, hbuf);
    }

    fin_gemm_kernel<<<mblocks * 5, 256, 0, stream>>>(hbuf, LDHB, fw1t, KP1, N_NODES, KP1,
                                                     fb1, fw2, partial);
    reduce_kernel<<<(N_NODES * NL + 255) / 256, 256, 0, stream>>>(partial, fb2, out);
}